// Round 5
// baseline (376.378 us; speedup 1.0000x reference)
//
#include <hip/hip_runtime.h>

// Downsampling_77214922047594 — B=4, N=8192, M=32768, K=16, C=128, G=8, f32 I/O
// Round 8: round-7 structure (passing) +
//  - gather: explicit 16-deep float4 load batch (force MLP; VGPRs free there)
//  - poll: ACQUIRE loads (round-2 proven-fresh semantics) at s_sleep(16) cadence

constexpr int NPB = 8192;            // N per batch
constexpr int BN  = 32768;           // total rows
constexpr int CH  = 128;
constexpr int KNB = 16;              // neighbors
constexpr int MS  = 32768;           // s_feats rows per batch
constexpr int NG  = 8;               // groups
constexpr int CG  = 16;              // channels per group
constexpr int RPB = 64;              // rows per block
constexpr int NBLK = BN / RPB;       // 512 blocks == 256 CU x 2 (co-resident)
constexpr int BPB  = NPB / RPB;      // 128 blocks per batch
constexpr int SUBN = NBLK / 8;       // arrivals per sub-counter
constexpr int XS = 152;              // LDS stride: 304B rows -> 2-way banks (free)
constexpr int WS = 152;

// ctl region (u32 index from ctl base, zeroed range [0,2048)):
//   stats replicas: [0, 1536)       = 3 layers * 8 replicas * 64 floats
//   sub-counters:   1536 + r*32     (128 B apart), r=0..7
//   global counter: 1792
//   release flag:   1824

typedef short short8 __attribute__((ext_vector_type(8)));
typedef float floatx4 __attribute__((ext_vector_type(4)));

static __device__ __forceinline__ unsigned short f2bs(float f) {
    unsigned int u = __builtin_bit_cast(unsigned int, f);
    unsigned int r = (u + 0x7fffu + ((u >> 16) & 1u)) >> 16;   // RNE
    return (unsigned short)r;
}

// ---------------- W transpose + bf16 cast + ctl zero ----------------
__global__ __launch_bounds__(256) void k_prep(
    const float* __restrict__ W1, const float* __restrict__ W2,
    const float* __restrict__ W3,
    unsigned short* __restrict__ Wt1, unsigned short* __restrict__ Wt2,
    unsigned short* __restrict__ Wt3, unsigned int* __restrict__ ctl)
{
    const int bi = blockIdx.x;          // 0..191
    if (bi == 0) {
        #pragma unroll
        for (int i = 0; i < 8; i++) ctl[threadIdx.x * 8 + i] = 0u;
    }
    const int w  = bi >> 6;
    const int i  = bi & 63;
    const int el = i * 256 + threadIdx.x;
    const int n  = el >> 7, k = el & 127;
    const float* W = (w == 0) ? W1 : (w == 1) ? W2 : W3;
    unsigned short* Wt = (w == 0) ? Wt1 : (w == 1) ? Wt2 : Wt3;
    Wt[n * 128 + k] = f2bs(W[k * 128 + n]);
}

// ---------------- fused kernel ----------------
__global__ __launch_bounds__(256, 2) void k_fused(
    const float* __restrict__ sf, const float* __restrict__ qp,
    const float* __restrict__ sp, const int* __restrict__ idx,
    const float* __restrict__ qf,
    const unsigned short* __restrict__ Wt1,
    const unsigned short* __restrict__ Wt2,
    const unsigned short* __restrict__ Wt3,
    const float* __restrict__ b1, const float* __restrict__ g1, const float* __restrict__ be1,
    const float* __restrict__ b2, const float* __restrict__ g2, const float* __restrict__ be2,
    const float* __restrict__ b3, const float* __restrict__ g3, const float* __restrict__ be3,
    float* __restrict__ ctlf,           // ctl base, zeroed by k_prep
    float* __restrict__ out)
{
    float* stats = ctlf;                               // 3*8*64 floats
    unsigned int* subs = (unsigned int*)(ctlf + 1536); // sub r at subs[r*32]
    unsigned int* gcnt = subs + 256;
    unsigned int* flag = subs + 288;

    // XCD swizzle: 2 XCDs per batch -> per-XCD gather working set = one batch
    const int p   = blockIdx.x;
    const int rep = p & 7;
    const int q   = p >> 3;                            // 0..63
    const int bi  = (rep >> 1) * BPB + (rep & 1) * 64 + q;
    const int b   = rep >> 1;
    const int t   = threadIdx.x;
    const int w   = t >> 6;
    const int l   = t & 63;
    const int lr  = l & 15;
    const int qd  = l >> 4;

    __shared__ unsigned short Xl[RPB * XS];     // 19456 B
    __shared__ unsigned short Wl[CH * WS];      // 38912 B
    __shared__ float2 stats_s[NG];
    __shared__ float red16[16];
    __shared__ float wv[RPB * KNB];
    __shared__ float winv[RPB];
    __shared__ float pw[4][16];

    float vals[8][4];                           // pre-GN h tile, lives across barriers

    auto stageW = [&](const unsigned short* __restrict__ Wt) {
        #pragma unroll
        for (int i = 0; i < 8; i++) {
            int el = i * 2048 + t * 8;
            short8 w8 = *(const short8*)(Wt + el);
            *(short8*)&Wl[(el >> 7) * WS + (el & 127)] = w8;
        }
    };

    // two-level arrival + ACQUIRE poll (fresh, low cadence); phase = 1,2,3
    auto gbar = [&](unsigned int phase) {
        __syncthreads();                  // drains vmcnt: block's atomics performed
        if (t == 0) {
            unsigned int so = __hip_atomic_fetch_add(subs + rep * 32, 1u,
                                 __ATOMIC_ACQ_REL, __HIP_MEMORY_SCOPE_AGENT);
            if (so == phase * SUBN - 1) {
                unsigned int go = __hip_atomic_fetch_add(gcnt, 1u,
                                     __ATOMIC_ACQ_REL, __HIP_MEMORY_SCOPE_AGENT);
                if (go == phase * 8 - 1)
                    __hip_atomic_store(flag, phase, __ATOMIC_RELEASE,
                                       __HIP_MEMORY_SCOPE_AGENT);
            }
            unsigned int v = __hip_atomic_load(flag, __ATOMIC_ACQUIRE,
                                               __HIP_MEMORY_SCOPE_AGENT);
            while (v < phase) {
                __builtin_amdgcn_s_sleep(16);
                v = __hip_atomic_load(flag, __ATOMIC_ACQUIRE,
                                      __HIP_MEMORY_SCOPE_AGENT);
            }
        }
        __syncthreads();
    };

    // MFMA X(64x128)@W(128x128), bias, keep f32 h in vals, block partials
    // -> 16 atomicAdds into this block's replica of layer L's stats
    auto do_gemm = [&](const float* __restrict__ bias, int L) {
        floatx4 acc[8] = {};
        #pragma unroll
        for (int kt = 0; kt < 4; kt++) {
            short8 a = *(const short8*)&Xl[(w * 16 + lr) * XS + kt * 32 + qd * 8];
            #pragma unroll
            for (int j = 0; j < 8; j++) {
                short8 bf = *(const short8*)&Wl[(j * 16 + lr) * WS + kt * 32 + qd * 8];
                acc[j] = __builtin_amdgcn_mfma_f32_16x16x32_bf16(a, bf, acc[j], 0, 0, 0);
            }
        }
        #pragma unroll
        for (int j = 0; j < 8; j++) {
            float bj = bias[j * 16 + lr];
            float ss = 0.f, qq = 0.f;
            #pragma unroll
            for (int r = 0; r < 4; r++) {
                float v = acc[j][r] + bj;
                vals[j][r] = v;
                ss += v; qq += v * v;
            }
            #pragma unroll
            for (int off = 32; off; off >>= 1) {
                ss += __shfl_down(ss, off);
                qq += __shfl_down(qq, off);
            }
            if (l == 0) { pw[w][j] = ss; pw[w][8 + j] = qq; }
        }
        __syncthreads();                  // waves done with Wl/Xl + pw ready
        if (t < 16)
            atomicAdd(stats + (L * 8 + rep) * 64 + b * 16 + t,
                      pw[0][t] + pw[1][t] + pw[2][t] + pw[3][t]);
    };

    // stats readback (sum 8 replicas, ACQUIRE) -> GN + LeakyReLU (+resid) -> Xl
    auto gn_apply = [&](int L, const float* __restrict__ g,
                        const float* __restrict__ be, const float* __restrict__ resid) {
        if (t < 16) {
            float s = 0.f;
            #pragma unroll
            for (int r = 0; r < 8; r++)
                s += __hip_atomic_load(stats + (L * 8 + r) * 64 + b * 16 + t,
                                       __ATOMIC_ACQUIRE, __HIP_MEMORY_SCOPE_AGENT);
            red16[t] = s;
        }
        __syncthreads();
        if (t < NG) {
            const float cnt = (float)(NPB * CG);
            float mean = red16[t] / cnt;
            float var  = red16[t + 8] / cnt - mean * mean;
            stats_s[t] = make_float2(mean, rsqrtf(var + 1e-5f));
        }
        __syncthreads();
        #pragma unroll
        for (int j = 0; j < 8; j++) {
            const int c = j * 16 + lr;
            float2 st = stats_s[j];
            float ga = g[c], bb = be[c];
            #pragma unroll
            for (int r = 0; r < 4; r++) {
                float y = (vals[j][r] - st.x) * st.y * ga + bb;
                y = (y >= 0.f) ? y : 0.1f * y;
                if (resid)
                    y += resid[((size_t)bi * RPB + w * 16 + qd * 4 + r) * CH + c];
                Xl[(w * 16 + qd * 4 + r) * XS + c] = f2bs(y);
            }
        }
        __syncthreads();                  // Xl ready for MFMA
    };

    // ---------------- phase A: W1 stage + IDW gather -> Xl ----------------
    stageW(Wt1);
    #pragma unroll
    for (int i = 0; i < 4; i++) {
        int pk = i * 256 + t;                    // (row, k) pair index
        int row = pk >> 4, k = pk & 15;
        size_t rg = (size_t)bi * RPB + row;
        float qx = qp[rg * 3 + 0], qy = qp[rg * 3 + 1], qz = qp[rg * 3 + 2];
        const float* spp = sp + (rg * KNB + k) * 3;
        float dx = spp[0] - qx, dy = spp[1] - qy, dz = spp[2] - qz;
        wv[pk] = 1.0f / (dx * dx + dy * dy + dz * dz + 1e-8f);
    }
    __syncthreads();
    if (t < RPB) {
        float s = 0.f;
        #pragma unroll
        for (int k = 0; k < KNB; k++) s += wv[t * KNB + k];
        winv[t] = 1.0f / s;
    }
    __syncthreads();
    {
        // explicit 16-deep load batch per row: force outstanding-load MLP.
        // VGPR budget is free here (vals[][] not yet live).
        const int grp = t >> 5, c4 = (t & 31) * 4;
        const float* base = sf + (size_t)b * MS * CH + c4;
        for (int rr = 0; rr < 8; rr++) {
            int row = grp * 8 + rr;
            size_t rg = (size_t)bi * RPB + row;
            const int4* ip4 = (const int4*)(idx + rg * KNB);
            int4 i0 = ip4[0], i1 = ip4[1], i2 = ip4[2], i3 = ip4[3];
            float4 f0  = *(const float4*)(base + (size_t)i0.x * CH);
            float4 f1  = *(const float4*)(base + (size_t)i0.y * CH);
            float4 f2  = *(const float4*)(base + (size_t)i0.z * CH);
            float4 f3  = *(const float4*)(base + (size_t)i0.w * CH);
            float4 f4  = *(const float4*)(base + (size_t)i1.x * CH);
            float4 f5  = *(const float4*)(base + (size_t)i1.y * CH);
            float4 f6  = *(const float4*)(base + (size_t)i1.z * CH);
            float4 f7  = *(const float4*)(base + (size_t)i1.w * CH);
            float4 f8  = *(const float4*)(base + (size_t)i2.x * CH);
            float4 f9  = *(const float4*)(base + (size_t)i2.y * CH);
            float4 f10 = *(const float4*)(base + (size_t)i2.z * CH);
            float4 f11 = *(const float4*)(base + (size_t)i2.w * CH);
            float4 f12 = *(const float4*)(base + (size_t)i3.x * CH);
            float4 f13 = *(const float4*)(base + (size_t)i3.y * CH);
            float4 f14 = *(const float4*)(base + (size_t)i3.z * CH);
            float4 f15 = *(const float4*)(base + (size_t)i3.w * CH);
            const float4* wr = (const float4*)(wv + row * KNB);
            float4 w0 = wr[0], w1 = wr[1], w2 = wr[2], w3 = wr[3];
            float ax, ay, az, aw;
            ax  = w0.x * f0.x;  ay  = w0.x * f0.y;  az  = w0.x * f0.z;  aw  = w0.x * f0.w;
            ax += w0.y * f1.x;  ay += w0.y * f1.y;  az += w0.y * f1.z;  aw += w0.y * f1.w;
            ax += w0.z * f2.x;  ay += w0.z * f2.y;  az += w0.z * f2.z;  aw += w0.z * f2.w;
            ax += w0.w * f3.x;  ay += w0.w * f3.y;  az += w0.w * f3.z;  aw += w0.w * f3.w;
            ax += w1.x * f4.x;  ay += w1.x * f4.y;  az += w1.x * f4.z;  aw += w1.x * f4.w;
            ax += w1.y * f5.x;  ay += w1.y * f5.y;  az += w1.y * f5.z;  aw += w1.y * f5.w;
            ax += w1.z * f6.x;  ay += w1.z * f6.y;  az += w1.z * f6.z;  aw += w1.z * f6.w;
            ax += w1.w * f7.x;  ay += w1.w * f7.y;  az += w1.w * f7.z;  aw += w1.w * f7.w;
            ax += w2.x * f8.x;  ay += w2.x * f8.y;  az += w2.x * f8.z;  aw += w2.x * f8.w;
            ax += w2.y * f9.x;  ay += w2.y * f9.y;  az += w2.y * f9.z;  aw += w2.y * f9.w;
            ax += w2.z * f10.x; ay += w2.z * f10.y; az += w2.z * f10.z; aw += w2.z * f10.w;
            ax += w2.w * f11.x; ay += w2.w * f11.y; az += w2.w * f11.z; aw += w2.w * f11.w;
            ax += w3.x * f12.x; ay += w3.x * f12.y; az += w3.x * f12.z; aw += w3.x * f12.w;
            ax += w3.y * f13.x; ay += w3.y * f13.y; az += w3.y * f13.z; aw += w3.y * f13.w;
            ax += w3.z * f14.x; ay += w3.z * f14.y; az += w3.z * f14.z; aw += w3.z * f14.w;
            ax += w3.w * f15.x; ay += w3.w * f15.y; az += w3.w * f15.z; aw += w3.w * f15.w;
            float wi = winv[row];
            ushort4 pkv;
            pkv.x = f2bs(ax * wi); pkv.y = f2bs(ay * wi);
            pkv.z = f2bs(az * wi); pkv.w = f2bs(aw * wi);
            *(ushort4*)&Xl[row * XS + c4] = pkv;
        }
    }
    __syncthreads();

    // ---------------- layer 1 ----------------
    do_gemm(b1, 0);
    stageW(Wt2);                                 // prefetch W2 under the barrier wait
    gbar(1);

    // ---------------- layer 2 ----------------
    gn_apply(0, g1, be1, nullptr);
    do_gemm(b2, 1);
    stageW(Wt3);
    gbar(2);

    // ---------------- layer 3 (with residual) ----------------
    gn_apply(1, g2, be2, qf);
    do_gemm(b3, 2);
    gbar(3);

    // ---------------- final GN + LeakyReLU -> f32 out ----------------
    if (t < 16) {
        float s = 0.f;
        #pragma unroll
        for (int r = 0; r < 8; r++)
            s += __hip_atomic_load(stats + (2 * 8 + r) * 64 + b * 16 + t,
                                   __ATOMIC_ACQUIRE, __HIP_MEMORY_SCOPE_AGENT);
        red16[t] = s;
    }
    __syncthreads();
    if (t < NG) {
        const float cnt = (float)(NPB * CG);
        float mean = red16[t] / cnt;
        float var  = red16[t + 8] / cnt - mean * mean;
        stats_s[t] = make_float2(mean, rsqrtf(var + 1e-5f));
    }
    __syncthreads();
    #pragma unroll
    for (int j = 0; j < 8; j++) {
        const int c = j * 16 + lr;
        float2 st = stats_s[j];
        float ga = g3[c], bb = be3[c];
        #pragma unroll
        for (int r = 0; r < 4; r++) {
            float y = (vals[j][r] - st.x) * st.y * ga + bb;
            y = (y >= 0.f) ? y : 0.1f * y;
            out[((size_t)bi * RPB + w * 16 + qd * 4 + r) * CH + c] = y;
        }
    }
}

extern "C" void kernel_launch(void* const* d_in, const int* in_sizes, int n_in,
                              void* d_out, int out_size, void* d_ws, size_t ws_size,
                              hipStream_t stream) {
    const float* qf  = (const float*)d_in[0];
    const float* sf  = (const float*)d_in[1];
    const float* qp  = (const float*)d_in[2];
    const float* sp  = (const float*)d_in[3];
    const int*   idx = (const int*)  d_in[4];
    const float* W1  = (const float*)d_in[5];
    const float* b1  = (const float*)d_in[6];
    const float* g1  = (const float*)d_in[7];
    const float* be1 = (const float*)d_in[8];
    const float* W2  = (const float*)d_in[9];
    const float* b2  = (const float*)d_in[10];
    const float* g2  = (const float*)d_in[11];
    const float* be2 = (const float*)d_in[12];
    const float* W3  = (const float*)d_in[13];
    const float* b3  = (const float*)d_in[14];
    const float* g3  = (const float*)d_in[15];
    const float* be3 = (const float*)d_in[16];

    char* ws = (char*)d_ws;
    unsigned short* Wt1 = (unsigned short*)(ws);
    unsigned short* Wt2 = (unsigned short*)(ws + 32768);
    unsigned short* Wt3 = (unsigned short*)(ws + 65536);
    float* ctlf = (float*)(ws + 98304);          // 2048-u32 ctl region
    float* out = (float*)d_out;

    k_prep<<<192, 256, 0, stream>>>(W1, W2, W3, Wt1, Wt2, Wt3,
                                    (unsigned int*)ctlf);
    k_fused<<<NBLK, 256, 0, stream>>>(sf, qp, sp, idx, qf,
                                      Wt1, Wt2, Wt3,
                                      b1, g1, be1,
                                      b2, g2, be2,
                                      b3, g3, be3,
                                      ctlf, out);
}

// Round 6
// 276.668 us; speedup vs baseline: 1.3604x; 1.3604x over previous
//
#include <hip/hip_runtime.h>

// Downsampling_77214922047594 — B=4, N=8192, M=32768, K=16, C=128, G=8, f32 I/O
// Round 9: two-kernel split for attribution + win:
//  - k_head: EXACT round-0 MODE0 structure (proven 45 µs; gather schedule
//    protected: no launch_bounds min-waves, no persistent regs, no lambdas)
//  - k_tail: fused GN1+GEMM2 / GN2+qf+GEMM3 / GN3->out with TWO grid barriers,
//    vals in registers, round-4 proven sync semantics (8-replica stats ACQ_REL
//    adds + ACQUIRE readback; two-level arrival; relaxed poll + acquire fence).

constexpr int NPB = 8192;            // N per batch
constexpr int BN  = 32768;           // total rows
constexpr int CH  = 128;
constexpr int KNB = 16;              // neighbors
constexpr int MS  = 32768;           // s_feats rows per batch
constexpr int NG  = 8;               // groups
constexpr int CG  = 16;              // channels per group
constexpr int RPB = 64;              // rows per block
constexpr int NBLK = BN / RPB;       // 512 blocks == 256 CU x 2 (co-resident)
constexpr int BPB  = NPB / RPB;      // 128 blocks per batch
constexpr int SUBN = NBLK / 8;       // arrivals per sub-counter
constexpr int XS = 152;              // LDS stride: 304B rows -> 2-way banks (free)
constexpr int WS = 152;

// ctl region (u32 index from ctl base, zeroed range [0,2048)):
//   stats replicas: [0, 1024)   = 2 layers (L2,L3) * 8 replicas * 64 floats
//   sub-counters:   1024 + r*32 (128 B apart), r=0..7
//   global counter: 1024 + 256
//   release flag:   1024 + 288

typedef short short8 __attribute__((ext_vector_type(8)));
typedef float floatx4 __attribute__((ext_vector_type(4)));

static __device__ __forceinline__ unsigned short f2bs(float f) {
    unsigned int u = __builtin_bit_cast(unsigned int, f);
    unsigned int r = (u + 0x7fffu + ((u >> 16) & 1u)) >> 16;   // RNE
    return (unsigned short)r;
}
static __device__ __forceinline__ float bs2f(unsigned short s) {
    unsigned int u = ((unsigned int)s) << 16;
    return __builtin_bit_cast(float, u);
}

// ---------------- W transpose + bf16 cast + ctl zero ----------------
__global__ __launch_bounds__(256) void k_prep(
    const float* __restrict__ W1, const float* __restrict__ W2,
    const float* __restrict__ W3,
    unsigned short* __restrict__ Wt1, unsigned short* __restrict__ Wt2,
    unsigned short* __restrict__ Wt3, unsigned int* __restrict__ ctl)
{
    const int bi = blockIdx.x;          // 0..191
    if (bi == 0) {
        #pragma unroll
        for (int i = 0; i < 8; i++) ctl[threadIdx.x * 8 + i] = 0u;
    }
    const int w  = bi >> 6;
    const int i  = bi & 63;
    const int el = i * 256 + threadIdx.x;
    const int n  = el >> 7, k = el & 127;
    const float* W = (w == 0) ? W1 : (w == 1) ? W2 : W3;
    unsigned short* Wt = (w == 0) ? Wt1 : (w == 1) ? Wt2 : Wt3;
    Wt[n * 128 + k] = f2bs(W[k * 128 + n]);
}

// ---------------- head: IDW gather + GEMM1 -> h1 bf16 + partials ----------------
// Structure copied from the proven 45-µs round-0 MODE0 pass.
__global__ __launch_bounds__(256) void k_head(
    const float* __restrict__ sf, const float* __restrict__ qp,
    const float* __restrict__ sp, const int* __restrict__ idx,
    const unsigned short* __restrict__ Wt,    // bf16 (n,k) 128x128
    const float* __restrict__ bias,           // b1
    unsigned short* __restrict__ hout,        // bf16 (BN,CH) pre-GN
    float* __restrict__ part_out)             // (NBLK,16)
{
    const int bi = blockIdx.x;
    const int t  = threadIdx.x;
    const int b  = bi / BPB;

    __shared__ unsigned short Xl[RPB * XS];
    __shared__ unsigned short Wl[CH * WS];
    __shared__ float wv[RPB * KNB];
    __shared__ float winv[RPB];
    __shared__ float pw[4][16];

    // ---- stage W ----
    #pragma unroll
    for (int i = 0; i < 8; i++) {
        int el = i * 2048 + t * 8;
        short8 w8 = *(const short8*)(Wt + el);
        *(short8*)&Wl[(el >> 7) * WS + (el & 127)] = w8;
    }

    // ---- IDW weights ----
    #pragma unroll
    for (int i = 0; i < 4; i++) {
        int p = i * 256 + t;                 // (row, k) pair index
        int row = p >> 4, k = p & 15;
        size_t rg = (size_t)bi * RPB + row;
        float qx = qp[rg * 3 + 0], qy = qp[rg * 3 + 1], qz = qp[rg * 3 + 2];
        const float* spp = sp + (rg * KNB + k) * 3;
        float dx = spp[0] - qx, dy = spp[1] - qy, dz = spp[2] - qz;
        wv[p] = 1.0f / (dx * dx + dy * dy + dz * dz + 1e-8f);
    }
    __syncthreads();
    if (t < RPB) {
        float s = 0.f;
        #pragma unroll
        for (int k = 0; k < KNB; k++) s += wv[t * KNB + k];
        winv[t] = 1.0f / s;
    }
    __syncthreads();
    // ---- gather: 8 groups of 32 lanes, each group 8 rows, float4 cols ----
    {
        const int grp = t >> 5, c4 = (t & 31) * 4;
        for (int rr = 0; rr < 8; rr++) {
            int row = grp * 8 + rr;
            size_t rg = (size_t)bi * RPB + row;
            const int* ip = idx + rg * KNB;
            float ax = 0.f, ay = 0.f, az = 0.f, aw = 0.f;
            #pragma unroll
            for (int k = 0; k < KNB; k++) {
                int j = ip[k];
                const float4 f = *(const float4*)(sf + ((size_t)b * MS + j) * CH + c4);
                float w = wv[row * KNB + k];
                ax += w * f.x; ay += w * f.y; az += w * f.z; aw += w * f.w;
            }
            float wi = winv[row];
            ushort4 pk;
            pk.x = f2bs(ax * wi); pk.y = f2bs(ay * wi);
            pk.z = f2bs(az * wi); pk.w = f2bs(aw * wi);
            *(ushort4*)&Xl[row * XS + c4] = pk;
        }
    }
    __syncthreads();

    // ---- MFMA: 4 waves x 16 rows; 8 n-tiles; K-loop 4 x 32 ----
    const int w  = t >> 6;
    const int l  = t & 63;
    const int lr = l & 15;
    const int qd = l >> 4;
    floatx4 acc[8] = {};
    #pragma unroll
    for (int kt = 0; kt < 4; kt++) {
        short8 a = *(const short8*)&Xl[(w * 16 + lr) * XS + kt * 32 + qd * 8];
        #pragma unroll
        for (int j = 0; j < 8; j++) {
            short8 bf = *(const short8*)&Wl[(j * 16 + lr) * WS + kt * 32 + qd * 8];
            acc[j] = __builtin_amdgcn_mfma_f32_16x16x32_bf16(a, bf, acc[j], 0, 0, 0);
        }
    }

    // ---- epilogue: bias, group partials, store h ----
    float vals[8][4];
    #pragma unroll
    for (int j = 0; j < 8; j++) {
        float bj = bias[j * 16 + lr];
        float ss = 0.f, qq = 0.f;
        #pragma unroll
        for (int r = 0; r < 4; r++) {
            float v = acc[j][r] + bj;
            vals[j][r] = v;
            ss += v; qq += v * v;
        }
        #pragma unroll
        for (int off = 32; off; off >>= 1) {
            ss += __shfl_down(ss, off);
            qq += __shfl_down(qq, off);
        }
        if (l == 0) { pw[w][j] = ss; pw[w][8 + j] = qq; }
    }
    #pragma unroll
    for (int j = 0; j < 8; j++)
        #pragma unroll
        for (int r = 0; r < 4; r++)
            Xl[(w * 16 + qd * 4 + r) * XS + j * 16 + lr] = f2bs(vals[j][r]);
    __syncthreads();
    if (t < 16)
        part_out[(size_t)bi * 16 + t] = pw[0][t] + pw[1][t] + pw[2][t] + pw[3][t];
    #pragma unroll
    for (int i = 0; i < 4; i++) {
        int flat = i * 2048 + t * 8;
        int row = flat >> 7, col = flat & 127;
        *(short8*)(hout + (size_t)bi * RPB * CH + flat) =
            *(const short8*)&Xl[row * XS + col];
    }
}

// ---------------- tail: GN1+GEMM2 | GN2+qf+GEMM3 | GN3 -> out ----------------
__global__ __launch_bounds__(256, 2) void k_tail(
    const unsigned short* __restrict__ h1, const float* __restrict__ p1,
    const float* __restrict__ qf,
    const unsigned short* __restrict__ Wt2,
    const unsigned short* __restrict__ Wt3,
    const float* __restrict__ g1, const float* __restrict__ be1,
    const float* __restrict__ b2, const float* __restrict__ g2, const float* __restrict__ be2,
    const float* __restrict__ b3, const float* __restrict__ g3, const float* __restrict__ be3,
    float* __restrict__ ctlf,           // ctl base, zeroed by k_prep
    float* __restrict__ out)
{
    float* stats = ctlf;                               // 2*8*64 floats
    unsigned int* subs = (unsigned int*)(ctlf + 1024); // sub r at subs[r*32]
    unsigned int* gcnt = subs + 256;
    unsigned int* flag = subs + 288;

    const int p   = blockIdx.x;
    const int rep = p & 7;
    const int q   = p >> 3;                            // 0..63
    const int bi  = (rep >> 1) * BPB + (rep & 1) * 64 + q;
    const int b   = rep >> 1;
    const int t   = threadIdx.x;
    const int w   = t >> 6;
    const int l   = t & 63;
    const int lr  = l & 15;
    const int qd  = l >> 4;

    __shared__ unsigned short Xl[RPB * XS];
    __shared__ unsigned short Wl[CH * WS];
    __shared__ float2 stats_s[NG];
    __shared__ float red[16][17];
    __shared__ float red16[16];
    __shared__ float pw[4][16];

    float vals[8][4];

    auto stageW = [&](const unsigned short* __restrict__ Wt) {
        #pragma unroll
        for (int i = 0; i < 8; i++) {
            int el = i * 2048 + t * 8;
            short8 w8 = *(const short8*)(Wt + el);
            *(short8*)&Wl[(el >> 7) * WS + (el & 127)] = w8;
        }
    };

    // two-level arrival + relaxed poll + acquire fence (round-4 proven)
    auto gbar = [&](unsigned int phase) {
        __syncthreads();
        if (t == 0) {
            unsigned int so = __hip_atomic_fetch_add(subs + rep * 32, 1u,
                                 __ATOMIC_ACQ_REL, __HIP_MEMORY_SCOPE_AGENT);
            if (so == phase * SUBN - 1) {
                unsigned int go = __hip_atomic_fetch_add(gcnt, 1u,
                                     __ATOMIC_ACQ_REL, __HIP_MEMORY_SCOPE_AGENT);
                if (go == phase * 8 - 1)
                    __hip_atomic_store(flag, phase, __ATOMIC_RELEASE,
                                       __HIP_MEMORY_SCOPE_AGENT);
            }
            unsigned int v = __hip_atomic_load(flag, __ATOMIC_RELAXED,
                                               __HIP_MEMORY_SCOPE_AGENT);
            while (v < phase) {
                __builtin_amdgcn_s_sleep(8);
                v = __hip_atomic_load(flag, __ATOMIC_RELAXED,
                                      __HIP_MEMORY_SCOPE_AGENT);
            }
            __builtin_amdgcn_fence(__ATOMIC_ACQUIRE, "agent");
        }
        __syncthreads();
    };

    auto do_gemm = [&](const float* __restrict__ bias, int L) {
        floatx4 acc[8] = {};
        #pragma unroll
        for (int kt = 0; kt < 4; kt++) {
            short8 a = *(const short8*)&Xl[(w * 16 + lr) * XS + kt * 32 + qd * 8];
            #pragma unroll
            for (int j = 0; j < 8; j++) {
                short8 bf = *(const short8*)&Wl[(j * 16 + lr) * WS + kt * 32 + qd * 8];
                acc[j] = __builtin_amdgcn_mfma_f32_16x16x32_bf16(a, bf, acc[j], 0, 0, 0);
            }
        }
        #pragma unroll
        for (int j = 0; j < 8; j++) {
            float bj = bias[j * 16 + lr];
            float ss = 0.f, qq = 0.f;
            #pragma unroll
            for (int r = 0; r < 4; r++) {
                float v = acc[j][r] + bj;
                vals[j][r] = v;
                ss += v; qq += v * v;
            }
            #pragma unroll
            for (int off = 32; off; off >>= 1) {
                ss += __shfl_down(ss, off);
                qq += __shfl_down(qq, off);
            }
            if (l == 0) { pw[w][j] = ss; pw[w][8 + j] = qq; }
        }
        __syncthreads();
        if (t < 16)
            atomicAdd(stats + (L * 8 + rep) * 64 + b * 16 + t,
                      pw[0][t] + pw[1][t] + pw[2][t] + pw[3][t]);
    };

    auto gn_apply = [&](int L, const float* __restrict__ g,
                        const float* __restrict__ be, const float* __restrict__ resid) {
        if (t < 16) {
            float s = 0.f;
            #pragma unroll
            for (int r = 0; r < 8; r++)
                s += __hip_atomic_load(stats + (L * 8 + r) * 64 + b * 16 + t,
                                       __ATOMIC_ACQUIRE, __HIP_MEMORY_SCOPE_AGENT);
            red16[t] = s;
        }
        __syncthreads();
        if (t < NG) {
            const float cnt = (float)(NPB * CG);
            float mean = red16[t] / cnt;
            float var  = red16[t + 8] / cnt - mean * mean;
            stats_s[t] = make_float2(mean, rsqrtf(var + 1e-5f));
        }
        __syncthreads();
        #pragma unroll
        for (int j = 0; j < 8; j++) {
            const int c = j * 16 + lr;
            float2 st = stats_s[j];
            float ga = g[c], bb = be[c];
            #pragma unroll
            for (int r = 0; r < 4; r++) {
                float y = (vals[j][r] - st.x) * st.y * ga + bb;
                y = (y >= 0.f) ? y : 0.1f * y;
                if (resid)
                    y += resid[((size_t)bi * RPB + w * 16 + qd * 4 + r) * CH + c];
                Xl[(w * 16 + qd * 4 + r) * XS + c] = f2bs(y);
            }
        }
        __syncthreads();
    };

    // ---- phase 1: stats1 from p1 (per-block re-reduce) + GN1(h1) -> Xl ----
    stageW(Wt2);
    {
        int j = t & 15, chunk = t >> 4;
        float acc = 0.f;
        #pragma unroll
        for (int i = 0; i < 8; i++)
            acc += p1[(size_t)(b * BPB + chunk * 8 + i) * 16 + j];
        red[chunk][j] = acc;
    }
    __syncthreads();
    if (t < NG) {
        float s = 0.f, q2 = 0.f;
        #pragma unroll
        for (int c = 0; c < 16; c++) { s += red[c][t]; q2 += red[c][t + 8]; }
        const float cnt = (float)(NPB * CG);
        float mean = s / cnt;
        float var  = q2 / cnt - mean * mean;
        stats_s[t] = make_float2(mean, rsqrtf(var + 1e-5f));
    }
    __syncthreads();
    #pragma unroll
    for (int i = 0; i < 4; i++) {
        int flat = i * 2048 + t * 8;
        int row = flat >> 7, col = flat & 127;
        size_t gidx = (size_t)bi * RPB * CH + flat;
        short8 hv = *(const short8*)(h1 + gidx);
        float2 st = stats_s[col >> 4];
        float4 g0 = *(const float4*)(g1 + col);
        float4 g1v = *(const float4*)(g1 + col + 4);
        float4 b0 = *(const float4*)(be1 + col);
        float4 b1v = *(const float4*)(be1 + col + 4);
        float gg[8] = {g0.x, g0.y, g0.z, g0.w, g1v.x, g1v.y, g1v.z, g1v.w};
        float bb[8] = {b0.x, b0.y, b0.z, b0.w, b1v.x, b1v.y, b1v.z, b1v.w};
        unsigned short ov[8];
        #pragma unroll
        for (int e = 0; e < 8; e++) {
            float v = bs2f((unsigned short)hv[e]);
            float y = (v - st.x) * st.y * gg[e] + bb[e];
            y = (y >= 0.f) ? y : 0.1f * y;
            ov[e] = f2bs(y);
        }
        *(short8*)&Xl[row * XS + col] = *(short8*)ov;
    }
    __syncthreads();

    // ---- layer 2 ----
    do_gemm(b2, 0);
    stageW(Wt3);
    gbar(1);

    // ---- layer 3 (with residual) ----
    gn_apply(0, g2, be2, qf);
    do_gemm(b3, 1);
    gbar(2);

    // ---- final GN + LeakyReLU -> f32 out ----
    if (t < 16) {
        float s = 0.f;
        #pragma unroll
        for (int r = 0; r < 8; r++)
            s += __hip_atomic_load(stats + (1 * 8 + r) * 64 + b * 16 + t,
                                   __ATOMIC_ACQUIRE, __HIP_MEMORY_SCOPE_AGENT);
        red16[t] = s;
    }
    __syncthreads();
    if (t < NG) {
        const float cnt = (float)(NPB * CG);
        float mean = red16[t] / cnt;
        float var  = red16[t + 8] / cnt - mean * mean;
        stats_s[t] = make_float2(mean, rsqrtf(var + 1e-5f));
    }
    __syncthreads();
    #pragma unroll
    for (int j = 0; j < 8; j++) {
        const int c = j * 16 + lr;
        float2 st = stats_s[j];
        float ga = g3[c], bb = be3[c];
        #pragma unroll
        for (int r = 0; r < 4; r++) {
            float y = (vals[j][r] - st.x) * st.y * ga + bb;
            y = (y >= 0.f) ? y : 0.1f * y;
            out[((size_t)bi * RPB + w * 16 + qd * 4 + r) * CH + c] = y;
        }
    }
}

extern "C" void kernel_launch(void* const* d_in, const int* in_sizes, int n_in,
                              void* d_out, int out_size, void* d_ws, size_t ws_size,
                              hipStream_t stream) {
    const float* qf  = (const float*)d_in[0];
    const float* sf  = (const float*)d_in[1];
    const float* qp  = (const float*)d_in[2];
    const float* sp  = (const float*)d_in[3];
    const int*   idx = (const int*)  d_in[4];
    const float* W1  = (const float*)d_in[5];
    const float* b1  = (const float*)d_in[6];
    const float* g1  = (const float*)d_in[7];
    const float* be1 = (const float*)d_in[8];
    const float* W2  = (const float*)d_in[9];
    const float* b2  = (const float*)d_in[10];
    const float* g2  = (const float*)d_in[11];
    const float* be2 = (const float*)d_in[12];
    const float* W3  = (const float*)d_in[13];
    const float* b3  = (const float*)d_in[14];
    const float* g3  = (const float*)d_in[15];
    const float* be3 = (const float*)d_in[16];

    char* ws = (char*)d_ws;
    unsigned short* Wt1 = (unsigned short*)(ws);
    unsigned short* Wt2 = (unsigned short*)(ws + 32768);
    unsigned short* Wt3 = (unsigned short*)(ws + 65536);
    float* ctlf = (float*)(ws + 98304);            // 2048-u32 ctl region
    float* p1   = (float*)(ws + 114688);           // (NBLK,16) f32 = 32 KB
    unsigned short* h1 = (unsigned short*)(ws + 196608);  // 8 MB bf16
    float* out = (float*)d_out;

    k_prep<<<192, 256, 0, stream>>>(W1, W2, W3, Wt1, Wt2, Wt3,
                                    (unsigned int*)ctlf);
    k_head<<<NBLK, 256, 0, stream>>>(sf, qp, sp, idx, Wt1, b1, h1, p1);
    k_tail<<<NBLK, 256, 0, stream>>>(h1, p1, qf, Wt2, Wt3,
                                     g1, be1,
                                     b2, g2, be2,
                                     b3, g3, be3,
                                     ctlf, out);
}

// Round 9
// 198.107 us; speedup vs baseline: 1.8999x; 1.3966x over previous
//
#include <hip/hip_runtime.h>

// Downsampling_77214922047594 — B=4, N=8192, M=32768, K=16, C=128, G=8, f32 I/O
// Round 10 (3rd submit; rounds 7/8 were broker/container infra failures, not
// kernel results — source audited: no hangs possible, all writes in bounds):
// proven 5-kernel barrier-free pipeline (round-0 = 195 µs bench best), mid
// passes rebuilt for latency-hiding:
//  - W2/W3 in fragment-major global layout; MFMA B-operand loaded directly
//    global->reg (1 KB coalesced per wave) — no W LDS tile, no staging phase
//  - mid LDS 59 KB -> ~21 KB => 2 -> 5+ blocks/CU (occupancy 22% -> ~60%)
//  - stats via partials + next-kernel re-reduce (round-0 scheme, no atomics)

constexpr int NPB = 8192;            // N per batch
constexpr int BN  = 32768;           // total rows
constexpr int CH  = 128;
constexpr int KNB = 16;              // neighbors
constexpr int MS  = 32768;           // s_feats rows per batch
constexpr int NG  = 8;               // groups
constexpr int CG  = 16;              // channels per group
constexpr int RPB = 64;              // rows per block
constexpr int NBLK = BN / RPB;       // 512 blocks
constexpr int BPB  = NPB / RPB;      // 128 blocks per batch
constexpr int XS = 152;              // LDS stride (shorts): 304B rows -> 2-way banks
constexpr int WS = 152;

typedef short short8 __attribute__((ext_vector_type(8)));
typedef float floatx4 __attribute__((ext_vector_type(4)));

static __device__ __forceinline__ unsigned short f2bs(float f) {
    unsigned int u = __builtin_bit_cast(unsigned int, f);
    unsigned int r = (u + 0x7fffu + ((u >> 16) & 1u)) >> 16;   // RNE
    return (unsigned short)r;
}
static __device__ __forceinline__ float bs2f(unsigned short s) {
    unsigned int u = ((unsigned int)s) << 16;
    return __builtin_bit_cast(float, u);
}

// ---------------- W prep ----------------
// w==0: Wt1[n][k] = bf16(W1[k][n])            (LDS-staged by k_head)
// w>0 : fragment-major Wf[((j*4+kt)*64+lane)*8+e] = bf16(W[k][n]),
//       n = j*16+lr, k = kt*32+qd*8+e, lane = qd*16+lr
//       => per (j,kt) a wave loads 1 KB contiguous (perfectly coalesced).
__global__ __launch_bounds__(256) void k_prep(
    const float* __restrict__ W1, const float* __restrict__ W2,
    const float* __restrict__ W3,
    unsigned short* __restrict__ Wt1, unsigned short* __restrict__ Wf2,
    unsigned short* __restrict__ Wf3)
{
    const int bi = blockIdx.x;          // 0..191
    const int w  = bi >> 6;
    const int i  = bi & 63;
    const int el = i * 256 + threadIdx.x;
    const int n  = el >> 7, k = el & 127;
    const float* W = (w == 0) ? W1 : (w == 1) ? W2 : W3;
    unsigned short v = f2bs(W[k * 128 + n]);
    if (w == 0) {
        Wt1[n * 128 + k] = v;
    } else {
        unsigned short* Wf = (w == 1) ? Wf2 : Wf3;
        int j = n >> 4, lr = n & 15;
        int kt = k >> 5, qd = (k >> 3) & 3, e = k & 7;
        Wf[(((j * 4 + kt) * 64) + (qd * 16 + lr)) * 8 + e] = v;
    }
}

// ---------------- head: IDW gather + GEMM1 -> h1 bf16 + partials ----------------
// Proven round-0/round-6 structure, unchanged.
__global__ __launch_bounds__(256) void k_head(
    const float* __restrict__ sf, const float* __restrict__ qp,
    const float* __restrict__ sp, const int* __restrict__ idx,
    const unsigned short* __restrict__ Wt,    // bf16 (n,k) 128x128
    const float* __restrict__ bias,           // b1
    unsigned short* __restrict__ hout,        // bf16 (BN,CH) pre-GN
    float* __restrict__ part_out)             // (NBLK,16)
{
    const int bi = blockIdx.x;
    const int t  = threadIdx.x;
    const int b  = bi / BPB;

    __shared__ unsigned short Xl[RPB * XS];
    __shared__ unsigned short Wl[CH * WS];
    __shared__ float wv[RPB * KNB];
    __shared__ float winv[RPB];
    __shared__ float pw[4][16];

    // ---- stage W ----
    #pragma unroll
    for (int i = 0; i < 8; i++) {
        int el = i * 2048 + t * 8;
        short8 w8 = *(const short8*)(Wt + el);
        *(short8*)&Wl[(el >> 7) * WS + (el & 127)] = w8;
    }

    // ---- IDW weights ----
    #pragma unroll
    for (int i = 0; i < 4; i++) {
        int p = i * 256 + t;                 // (row, k) pair index
        int row = p >> 4, k = p & 15;
        size_t rg = (size_t)bi * RPB + row;
        float qx = qp[rg * 3 + 0], qy = qp[rg * 3 + 1], qz = qp[rg * 3 + 2];
        const float* spp = sp + (rg * KNB + k) * 3;
        float dx = spp[0] - qx, dy = spp[1] - qy, dz = spp[2] - qz;
        wv[p] = 1.0f / (dx * dx + dy * dy + dz * dz + 1e-8f);
    }
    __syncthreads();
    if (t < RPB) {
        float s = 0.f;
        #pragma unroll
        for (int k = 0; k < KNB; k++) s += wv[t * KNB + k];
        winv[t] = 1.0f / s;
    }
    __syncthreads();
    // ---- gather ----
    {
        const int grp = t >> 5, c4 = (t & 31) * 4;
        for (int rr = 0; rr < 8; rr++) {
            int row = grp * 8 + rr;
            size_t rg = (size_t)bi * RPB + row;
            const int* ip = idx + rg * KNB;
            float ax = 0.f, ay = 0.f, az = 0.f, aw = 0.f;
            #pragma unroll
            for (int k = 0; k < KNB; k++) {
                int j = ip[k];
                const float4 f = *(const float4*)(sf + ((size_t)b * MS + j) * CH + c4);
                float w = wv[row * KNB + k];
                ax += w * f.x; ay += w * f.y; az += w * f.z; aw += w * f.w;
            }
            float wi = winv[row];
            ushort4 pk;
            pk.x = f2bs(ax * wi); pk.y = f2bs(ay * wi);
            pk.z = f2bs(az * wi); pk.w = f2bs(aw * wi);
            *(ushort4*)&Xl[row * XS + c4] = pk;
        }
    }
    __syncthreads();

    // ---- MFMA ----
    const int w  = t >> 6;
    const int l  = t & 63;
    const int lr = l & 15;
    const int qd = l >> 4;
    floatx4 acc[8] = {};
    #pragma unroll
    for (int kt = 0; kt < 4; kt++) {
        short8 a = *(const short8*)&Xl[(w * 16 + lr) * XS + kt * 32 + qd * 8];
        #pragma unroll
        for (int j = 0; j < 8; j++) {
            short8 bf = *(const short8*)&Wl[(j * 16 + lr) * WS + kt * 32 + qd * 8];
            acc[j] = __builtin_amdgcn_mfma_f32_16x16x32_bf16(a, bf, acc[j], 0, 0, 0);
        }
    }

    // ---- epilogue ----
    float vals[8][4];
    #pragma unroll
    for (int j = 0; j < 8; j++) {
        float bj = bias[j * 16 + lr];
        float ss = 0.f, qq = 0.f;
        #pragma unroll
        for (int r = 0; r < 4; r++) {
            float v = acc[j][r] + bj;
            vals[j][r] = v;
            ss += v; qq += v * v;
        }
        #pragma unroll
        for (int off = 32; off; off >>= 1) {
            ss += __shfl_down(ss, off);
            qq += __shfl_down(qq, off);
        }
        if (l == 0) { pw[w][j] = ss; pw[w][8 + j] = qq; }
    }
    #pragma unroll
    for (int j = 0; j < 8; j++)
        #pragma unroll
        for (int r = 0; r < 4; r++)
            Xl[(w * 16 + qd * 4 + r) * XS + j * 16 + lr] = f2bs(vals[j][r]);
    __syncthreads();
    if (t < 16)
        part_out[(size_t)bi * 16 + t] = pw[0][t] + pw[1][t] + pw[2][t] + pw[3][t];
    #pragma unroll
    for (int i = 0; i < 4; i++) {
        int flat = i * 2048 + t * 8;
        int row = flat >> 7, col = flat & 127;
        *(short8*)(hout + (size_t)bi * RPB * CH + flat) =
            *(const short8*)&Xl[row * XS + col];
    }
}

// ---------------- mid: GN(h_prev)+act(+resid) -> X; X @ W -> h + partials ----
// RESID=0: layer2; RESID=1: layer3 (adds qf AFTER activation).
// W read directly from global fragment-major Wf (no LDS tile -> ~21 KB LDS).
template <int RESID>
__global__ __launch_bounds__(256) void k_mid(
    const unsigned short* __restrict__ hin,   // bf16 pre-GN h
    const float* __restrict__ part_in,        // (NBLK,16)
    const float* __restrict__ gamma,          // prev layer GN
    const float* __restrict__ beta,
    const float* __restrict__ qf,             // residual f32 (RESID)
    const unsigned short* __restrict__ Wf,    // fragment-major bf16 128x128
    const float* __restrict__ bias,           // this layer's bias
    unsigned short* __restrict__ hout,        // bf16 (BN,CH) pre-GN
    float* __restrict__ part_out)             // (NBLK,16)
{
    const int bi = blockIdx.x;
    const int t  = threadIdx.x;
    const int b  = bi / BPB;

    __shared__ unsigned short Xl[RPB * XS];       // 19456 B
    __shared__ float red[16][17];
    __shared__ float2 stats_s[NG];
    __shared__ float pw[4][16];

    // ---- in-block reduce of prev-pass partials -> stats ----
    {
        int j = t & 15, chunk = t >> 4;
        float acc = 0.f;
        #pragma unroll
        for (int i = 0; i < 8; i++)
            acc += part_in[(size_t)(b * BPB + chunk * 8 + i) * 16 + j];
        red[chunk][j] = acc;
    }
    __syncthreads();
    if (t < NG) {
        float s = 0.f, q = 0.f;
        #pragma unroll
        for (int c = 0; c < 16; c++) { s += red[c][t]; q += red[c][t + 8]; }
        const float cnt = (float)(NPB * CG);
        float mean = s / cnt;
        float var  = q / cnt - mean * mean;
        stats_s[t] = make_float2(mean, rsqrtf(var + 1e-5f));
    }
    __syncthreads();
    // ---- GN + LeakyReLU (+resid) -> bf16 X tile ----
    #pragma unroll
    for (int i = 0; i < 4; i++) {
        int flat = i * 2048 + t * 8;
        int row = flat >> 7, col = flat & 127;
        size_t gidx = (size_t)bi * RPB * CH + flat;
        short8 hv = *(const short8*)(hin + gidx);
        float2 st = stats_s[col >> 4];
        float4 g0 = *(const float4*)(gamma + col);
        float4 g1 = *(const float4*)(gamma + col + 4);
        float4 b0 = *(const float4*)(beta + col);
        float4 b1 = *(const float4*)(beta + col + 4);
        float gg[8] = {g0.x, g0.y, g0.z, g0.w, g1.x, g1.y, g1.z, g1.w};
        float bb[8] = {b0.x, b0.y, b0.z, b0.w, b1.x, b1.y, b1.z, b1.w};
        float re[8];
        if (RESID) {
            float4 r0 = *(const float4*)(qf + gidx);
            float4 r1 = *(const float4*)(qf + gidx + 4);
            re[0]=r0.x; re[1]=r0.y; re[2]=r0.z; re[3]=r0.w;
            re[4]=r1.x; re[5]=r1.y; re[6]=r1.z; re[7]=r1.w;
        }
        unsigned short ov[8];
        #pragma unroll
        for (int e = 0; e < 8; e++) {
            float v = bs2f((unsigned short)hv[e]);
            float y = (v - st.x) * st.y * gg[e] + bb[e];
            y = (y >= 0.f) ? y : 0.1f * y;
            if (RESID) y += re[e];
            ov[e] = f2bs(y);
        }
        *(short8*)&Xl[row * XS + col] = *(short8*)ov;
    }
    __syncthreads();

    // ---- MFMA, W fragments straight from global (coalesced 1 KB/wave) ----
    const int w  = t >> 6;
    const int l  = t & 63;
    const int lr = l & 15;
    const int qd = l >> 4;
    floatx4 acc[8] = {};
    #pragma unroll
    for (int kt = 0; kt < 4; kt++) {
        short8 a = *(const short8*)&Xl[(w * 16 + lr) * XS + kt * 32 + qd * 8];
        #pragma unroll
        for (int j = 0; j < 8; j++) {
            short8 bf = *(const short8*)(Wf + (((j * 4 + kt) * 64) + l) * 8);
            acc[j] = __builtin_amdgcn_mfma_f32_16x16x32_bf16(a, bf, acc[j], 0, 0, 0);
        }
    }

    // ---- epilogue: bias, group partials, store h ----
    float vals[8][4];
    #pragma unroll
    for (int j = 0; j < 8; j++) {
        float bj = bias[j * 16 + lr];
        float ss = 0.f, qq = 0.f;
        #pragma unroll
        for (int r = 0; r < 4; r++) {
            float v = acc[j][r] + bj;
            vals[j][r] = v;
            ss += v; qq += v * v;
        }
        #pragma unroll
        for (int off = 32; off; off >>= 1) {
            ss += __shfl_down(ss, off);
            qq += __shfl_down(qq, off);
        }
        if (l == 0) { pw[w][j] = ss; pw[w][8 + j] = qq; }
    }
    #pragma unroll
    for (int j = 0; j < 8; j++)
        #pragma unroll
        for (int r = 0; r < 4; r++)
            Xl[(w * 16 + qd * 4 + r) * XS + j * 16 + lr] = f2bs(vals[j][r]);
    __syncthreads();
    if (t < 16)
        part_out[(size_t)bi * 16 + t] = pw[0][t] + pw[1][t] + pw[2][t] + pw[3][t];
    #pragma unroll
    for (int i = 0; i < 4; i++) {
        int flat = i * 2048 + t * 8;
        int row = flat >> 7, col = flat & 127;
        *(short8*)(hout + (size_t)bi * RPB * CH + flat) =
            *(const short8*)&Xl[row * XS + col];
    }
}

// ---------------- final GN + LeakyReLU -> f32 out ----------------
__global__ __launch_bounds__(256) void k_out(
    const unsigned short* __restrict__ hin, const float* __restrict__ part_in,
    const float* __restrict__ gamma, const float* __restrict__ beta,
    float* __restrict__ out)
{
    const int bi = blockIdx.x;
    const int t  = threadIdx.x;
    const int b  = bi / BPB;
    __shared__ float red[16][17];
    __shared__ float2 stats_s[NG];
    {
        int j = t & 15, chunk = t >> 4;
        float acc = 0.f;
        #pragma unroll
        for (int i = 0; i < 8; i++)
            acc += part_in[(size_t)(b * BPB + chunk * 8 + i) * 16 + j];
        red[chunk][j] = acc;
    }
    __syncthreads();
    if (t < NG) {
        float s = 0.f, q = 0.f;
        #pragma unroll
        for (int c = 0; c < 16; c++) { s += red[c][t]; q += red[c][t + 8]; }
        const float cnt = (float)(NPB * CG);
        float mean = s / cnt;
        float var  = q / cnt - mean * mean;
        stats_s[t] = make_float2(mean, rsqrtf(var + 1e-5f));
    }
    __syncthreads();
    #pragma unroll
    for (int i = 0; i < 4; i++) {
        int flat = i * 2048 + t * 8;
        int col = flat & 127;
        size_t gidx = (size_t)bi * RPB * CH + flat;
        short8 hv = *(const short8*)(hin + gidx);
        float2 st = stats_s[col >> 4];
        float4 g0 = *(const float4*)(gamma + col);
        float4 g1 = *(const float4*)(gamma + col + 4);
        float4 b0 = *(const float4*)(beta + col);
        float4 b1 = *(const float4*)(beta + col + 4);
        float gg[8] = {g0.x, g0.y, g0.z, g0.w, g1.x, g1.y, g1.z, g1.w};
        float bb[8] = {b0.x, b0.y, b0.z, b0.w, b1.x, b1.y, b1.z, b1.w};
        float o[8];
        #pragma unroll
        for (int e = 0; e < 8; e++) {
            float v = bs2f((unsigned short)hv[e]);
            float y = (v - st.x) * st.y * gg[e] + bb[e];
            o[e] = (y >= 0.f) ? y : 0.1f * y;
        }
        float4 o0 = {o[0], o[1], o[2], o[3]};
        float4 o1 = {o[4], o[5], o[6], o[7]};
        *(float4*)(out + gidx)     = o0;
        *(float4*)(out + gidx + 4) = o1;
    }
}

extern "C" void kernel_launch(void* const* d_in, const int* in_sizes, int n_in,
                              void* d_out, int out_size, void* d_ws, size_t ws_size,
                              hipStream_t stream) {
    const float* qf  = (const float*)d_in[0];
    const float* sf  = (const float*)d_in[1];
    const float* qp  = (const float*)d_in[2];
    const float* sp  = (const float*)d_in[3];
    const int*   idx = (const int*)  d_in[4];
    const float* W1  = (const float*)d_in[5];
    const float* b1  = (const float*)d_in[6];
    const float* g1  = (const float*)d_in[7];
    const float* be1 = (const float*)d_in[8];
    const float* W2  = (const float*)d_in[9];
    const float* b2  = (const float*)d_in[10];
    const float* g2  = (const float*)d_in[11];
    const float* be2 = (const float*)d_in[12];
    const float* W3  = (const float*)d_in[13];
    const float* b3  = (const float*)d_in[14];
    const float* g3  = (const float*)d_in[15];
    const float* be3 = (const float*)d_in[16];

    char* ws = (char*)d_ws;
    unsigned short* Wt1 = (unsigned short*)(ws);
    unsigned short* Wf2 = (unsigned short*)(ws + 32768);
    unsigned short* Wf3 = (unsigned short*)(ws + 65536);
    float* p1 = (float*)(ws + 98304);
    float* p2 = (float*)(ws + 131072);
    float* p3 = (float*)(ws + 163840);
    unsigned short* h1 = (unsigned short*)(ws + 196608);
    unsigned short* h2 = (unsigned short*)(ws + 196608 + 8388608);
    unsigned short* h3 = (unsigned short*)(ws + 196608 + 2 * 8388608);
    float* out = (float*)d_out;

    k_prep<<<192, 256, 0, stream>>>(W1, W2, W3, Wt1, Wf2, Wf3);
    k_head<<<NBLK, 256, 0, stream>>>(sf, qp, sp, idx, Wt1, b1, h1, p1);
    k_mid<0><<<NBLK, 256, 0, stream>>>(h1, p1, g1, be1, nullptr, Wf2, b2, h2, p2);
    k_mid<1><<<NBLK, 256, 0, stream>>>(h2, p2, g2, be2, qf, Wf3, b3, h3, p3);
    k_out<<<NBLK, 256, 0, stream>>>(h3, p3, g3, be3, out);
}

// Round 10
// 195.152 us; speedup vs baseline: 1.9286x; 1.0151x over previous
//
#include <hip/hip_runtime.h>

// Downsampling_77214922047594 — B=4, N=8192, M=32768, K=16, C=128, G=8, f32 I/O
// Round 11: thin passes get REAL parallelism. Round 9 raised the occupancy
// ceiling but grid stayed 512 blocks = 2/CU (8 waves/CU) — no-op. Now:
//  - k_head (gather+GEMM1): unchanged, 512 blocks, proven ~45 µs
//  - k_mid/k_out: 16-row tiles -> 2048 blocks = 8 blocks/CU = 32 waves/CU (4x)
//    per-wave MFMA = column-split (2 n-tiles x 4 kt); ~6 KB LDS; W from global
//  - partials now (2048,16) out of mids; re-reduce parameterized by rows/batch

constexpr int NPB = 8192;            // N per batch
constexpr int BN  = 32768;           // total rows
constexpr int CH  = 128;
constexpr int KNB = 16;              // neighbors
constexpr int MS  = 32768;           // s_feats rows per batch
constexpr int NG  = 8;               // groups
constexpr int CG  = 16;              // channels per group
constexpr int RPB = 64;              // k_head rows per block
constexpr int NBLK = BN / RPB;       // 512 blocks (head)
constexpr int BPB  = NPB / RPB;      // 128 head blocks per batch
constexpr int MRPB = 16;             // mid/out rows per block
constexpr int MNBLK = BN / MRPB;     // 2048 blocks (mid/out)
constexpr int MBPB  = NPB / MRPB;    // 512 mid blocks per batch
constexpr int XS = 152;              // LDS stride (shorts): 304B rows -> 2-way banks
constexpr int WS = 152;

typedef short short8 __attribute__((ext_vector_type(8)));
typedef float floatx4 __attribute__((ext_vector_type(4)));

static __device__ __forceinline__ unsigned short f2bs(float f) {
    unsigned int u = __builtin_bit_cast(unsigned int, f);
    unsigned int r = (u + 0x7fffu + ((u >> 16) & 1u)) >> 16;   // RNE
    return (unsigned short)r;
}
static __device__ __forceinline__ float bs2f(unsigned short s) {
    unsigned int u = ((unsigned int)s) << 16;
    return __builtin_bit_cast(float, u);
}

// ---------------- W prep ----------------
// w==0: Wt1[n][k] = bf16(W1[k][n])            (LDS-staged by k_head)
// w>0 : fragment-major Wf[((j*4+kt)*64+lane)*8+e] = bf16(W[k][n]),
//       n = j*16+lr, k = kt*32+qd*8+e, lane = qd*16+lr
__global__ __launch_bounds__(256) void k_prep(
    const float* __restrict__ W1, const float* __restrict__ W2,
    const float* __restrict__ W3,
    unsigned short* __restrict__ Wt1, unsigned short* __restrict__ Wf2,
    unsigned short* __restrict__ Wf3)
{
    const int bi = blockIdx.x;          // 0..191
    const int w  = bi >> 6;
    const int i  = bi & 63;
    const int el = i * 256 + threadIdx.x;
    const int n  = el >> 7, k = el & 127;
    const float* W = (w == 0) ? W1 : (w == 1) ? W2 : W3;
    unsigned short v = f2bs(W[k * 128 + n]);
    if (w == 0) {
        Wt1[n * 128 + k] = v;
    } else {
        unsigned short* Wf = (w == 1) ? Wf2 : Wf3;
        int j = n >> 4, lr = n & 15;
        int kt = k >> 5, qd = (k >> 3) & 3, e = k & 7;
        Wf[(((j * 4 + kt) * 64) + (qd * 16 + lr)) * 8 + e] = v;
    }
}

// ---------------- head: IDW gather + GEMM1 -> h1 bf16 + partials ----------------
// Proven structure, unchanged. Partials: (NBLK=512, 16) = 128 rows/batch.
__global__ __launch_bounds__(256) void k_head(
    const float* __restrict__ sf, const float* __restrict__ qp,
    const float* __restrict__ sp, const int* __restrict__ idx,
    const unsigned short* __restrict__ Wt,    // bf16 (n,k) 128x128
    const float* __restrict__ bias,           // b1
    unsigned short* __restrict__ hout,        // bf16 (BN,CH) pre-GN
    float* __restrict__ part_out)             // (NBLK,16)
{
    const int bi = blockIdx.x;
    const int t  = threadIdx.x;
    const int b  = bi / BPB;

    __shared__ unsigned short Xl[RPB * XS];
    __shared__ unsigned short Wl[CH * WS];
    __shared__ float wv[RPB * KNB];
    __shared__ float winv[RPB];
    __shared__ float pw[4][16];

    // ---- stage W ----
    #pragma unroll
    for (int i = 0; i < 8; i++) {
        int el = i * 2048 + t * 8;
        short8 w8 = *(const short8*)(Wt + el);
        *(short8*)&Wl[(el >> 7) * WS + (el & 127)] = w8;
    }

    // ---- IDW weights ----
    #pragma unroll
    for (int i = 0; i < 4; i++) {
        int p = i * 256 + t;                 // (row, k) pair index
        int row = p >> 4, k = p & 15;
        size_t rg = (size_t)bi * RPB + row;
        float qx = qp[rg * 3 + 0], qy = qp[rg * 3 + 1], qz = qp[rg * 3 + 2];
        const float* spp = sp + (rg * KNB + k) * 3;
        float dx = spp[0] - qx, dy = spp[1] - qy, dz = spp[2] - qz;
        wv[p] = 1.0f / (dx * dx + dy * dy + dz * dz + 1e-8f);
    }
    __syncthreads();
    if (t < RPB) {
        float s = 0.f;
        #pragma unroll
        for (int k = 0; k < KNB; k++) s += wv[t * KNB + k];
        winv[t] = 1.0f / s;
    }
    __syncthreads();
    // ---- gather ----
    {
        const int grp = t >> 5, c4 = (t & 31) * 4;
        for (int rr = 0; rr < 8; rr++) {
            int row = grp * 8 + rr;
            size_t rg = (size_t)bi * RPB + row;
            const int* ip = idx + rg * KNB;
            float ax = 0.f, ay = 0.f, az = 0.f, aw = 0.f;
            #pragma unroll
            for (int k = 0; k < KNB; k++) {
                int j = ip[k];
                const float4 f = *(const float4*)(sf + ((size_t)b * MS + j) * CH + c4);
                float w = wv[row * KNB + k];
                ax += w * f.x; ay += w * f.y; az += w * f.z; aw += w * f.w;
            }
            float wi = winv[row];
            ushort4 pk;
            pk.x = f2bs(ax * wi); pk.y = f2bs(ay * wi);
            pk.z = f2bs(az * wi); pk.w = f2bs(aw * wi);
            *(ushort4*)&Xl[row * XS + c4] = pk;
        }
    }
    __syncthreads();

    // ---- MFMA ----
    const int w  = t >> 6;
    const int l  = t & 63;
    const int lr = l & 15;
    const int qd = l >> 4;
    floatx4 acc[8] = {};
    #pragma unroll
    for (int kt = 0; kt < 4; kt++) {
        short8 a = *(const short8*)&Xl[(w * 16 + lr) * XS + kt * 32 + qd * 8];
        #pragma unroll
        for (int j = 0; j < 8; j++) {
            short8 bf = *(const short8*)&Wl[(j * 16 + lr) * WS + kt * 32 + qd * 8];
            acc[j] = __builtin_amdgcn_mfma_f32_16x16x32_bf16(a, bf, acc[j], 0, 0, 0);
        }
    }

    // ---- epilogue ----
    float vals[8][4];
    #pragma unroll
    for (int j = 0; j < 8; j++) {
        float bj = bias[j * 16 + lr];
        float ss = 0.f, qq = 0.f;
        #pragma unroll
        for (int r = 0; r < 4; r++) {
            float v = acc[j][r] + bj;
            vals[j][r] = v;
            ss += v; qq += v * v;
        }
        #pragma unroll
        for (int off = 32; off; off >>= 1) {
            ss += __shfl_down(ss, off);
            qq += __shfl_down(qq, off);
        }
        if (l == 0) { pw[w][j] = ss; pw[w][8 + j] = qq; }
    }
    #pragma unroll
    for (int j = 0; j < 8; j++)
        #pragma unroll
        for (int r = 0; r < 4; r++)
            Xl[(w * 16 + qd * 4 + r) * XS + j * 16 + lr] = f2bs(vals[j][r]);
    __syncthreads();
    if (t < 16)
        part_out[(size_t)bi * 16 + t] = pw[0][t] + pw[1][t] + pw[2][t] + pw[3][t];
    #pragma unroll
    for (int i = 0; i < 4; i++) {
        int flat = i * 2048 + t * 8;
        int row = flat >> 7, col = flat & 127;
        *(short8*)(hout + (size_t)bi * RPB * CH + flat) =
            *(const short8*)&Xl[row * XS + col];
    }
}

// ---------------- mid: 16-row tile, 2048 blocks, 32 waves/CU ----------------
// PPB = partial rows per batch in part_in (128 from k_head, 512 from a mid).
// Wave w owns n-tiles {2w, 2w+1} over all 16 rows (column-split MFMA).
template <int RESID, int PPB>
__global__ __launch_bounds__(256) void k_mid(
    const unsigned short* __restrict__ hin,   // bf16 pre-GN h
    const float* __restrict__ part_in,
    const float* __restrict__ gamma,          // prev layer GN
    const float* __restrict__ beta,
    const float* __restrict__ qf,             // residual f32 (RESID)
    const unsigned short* __restrict__ Wf,    // fragment-major bf16 128x128
    const float* __restrict__ bias,           // this layer's bias
    unsigned short* __restrict__ hout,        // bf16 (BN,CH) pre-GN
    float* __restrict__ part_out)             // (MNBLK,16)
{
    const int bi = blockIdx.x;                // 0..2047
    const int t  = threadIdx.x;
    const int b  = bi / MBPB;

    __shared__ unsigned short Xl[MRPB * XS];  // 4864 B
    __shared__ float red[16][17];
    __shared__ float2 stats_s[NG];
    __shared__ float pw[4][4];

    // ---- stats re-reduce ----
    constexpr int R = PPB / 16;
    {
        int j = t & 15, chunk = t >> 4;
        float acc = 0.f;
        #pragma unroll
        for (int i = 0; i < R; i++)
            acc += part_in[(size_t)(b * PPB + chunk * R + i) * 16 + j];
        red[chunk][j] = acc;
    }
    __syncthreads();
    if (t < NG) {
        float s = 0.f, q = 0.f;
        #pragma unroll
        for (int c = 0; c < 16; c++) { s += red[c][t]; q += red[c][t + 8]; }
        const float cnt = (float)(NPB * CG);
        float mean = s / cnt;
        float var  = q / cnt - mean * mean;
        stats_s[t] = make_float2(mean, rsqrtf(var + 1e-5f));
    }
    __syncthreads();

    // ---- GN + LeakyReLU (+resid) -> bf16 X tile (one short8 per thread) ----
    {
        int flat = t * 8;
        int row = flat >> 7, col = flat & 127;
        size_t gidx = (size_t)bi * (MRPB * CH) + flat;
        short8 hv = *(const short8*)(hin + gidx);
        float2 st = stats_s[col >> 4];
        float4 g0 = *(const float4*)(gamma + col);
        float4 g1 = *(const float4*)(gamma + col + 4);
        float4 b0 = *(const float4*)(beta + col);
        float4 b1 = *(const float4*)(beta + col + 4);
        float gg[8] = {g0.x, g0.y, g0.z, g0.w, g1.x, g1.y, g1.z, g1.w};
        float bb[8] = {b0.x, b0.y, b0.z, b0.w, b1.x, b1.y, b1.z, b1.w};
        float re[8];
        if (RESID) {
            float4 r0 = *(const float4*)(qf + gidx);
            float4 r1 = *(const float4*)(qf + gidx + 4);
            re[0]=r0.x; re[1]=r0.y; re[2]=r0.z; re[3]=r0.w;
            re[4]=r1.x; re[5]=r1.y; re[6]=r1.z; re[7]=r1.w;
        }
        unsigned short ov[8];
        #pragma unroll
        for (int e = 0; e < 8; e++) {
            float v = bs2f((unsigned short)hv[e]);
            float y = (v - st.x) * st.y * gg[e] + bb[e];
            y = (y >= 0.f) ? y : 0.1f * y;
            if (RESID) y += re[e];
            ov[e] = f2bs(y);
        }
        *(short8*)&Xl[row * XS + col] = *(short8*)ov;
    }
    __syncthreads();

    // ---- MFMA: wave w -> n-tiles {2w, 2w+1}, rows 0..15 ----
    const int w  = t >> 6;
    const int l  = t & 63;
    const int lr = l & 15;
    const int qd = l >> 4;
    floatx4 acc2[2] = {};
    #pragma unroll
    for (int kt = 0; kt < 4; kt++) {
        short8 a = *(const short8*)&Xl[lr * XS + kt * 32 + qd * 8];
        #pragma unroll
        for (int jj = 0; jj < 2; jj++) {
            int j = w * 2 + jj;
            short8 bf = *(const short8*)(Wf + (((j * 4 + kt) * 64) + l) * 8);
            acc2[jj] = __builtin_amdgcn_mfma_f32_16x16x32_bf16(a, bf, acc2[jj], 0, 0, 0);
        }
    }

    // ---- epilogue: bias, group partials ----
    float vals[2][4];
    #pragma unroll
    for (int jj = 0; jj < 2; jj++) {
        int j = w * 2 + jj;
        float bj = bias[j * 16 + lr];
        float ss = 0.f, qq = 0.f;
        #pragma unroll
        for (int r = 0; r < 4; r++) {
            float v = acc2[jj][r] + bj;
            vals[jj][r] = v;
            ss += v; qq += v * v;
        }
        #pragma unroll
        for (int off = 32; off; off >>= 1) {
            ss += __shfl_down(ss, off);
            qq += __shfl_down(qq, off);
        }
        if (l == 0) { pw[w][jj] = ss; pw[w][2 + jj] = qq; }
    }
    __syncthreads();   // all waves done READING Xl (A frags shared) + pw ready

    // ---- scatter C into Xl (waves own disjoint col ranges) + partials out ----
    #pragma unroll
    for (int jj = 0; jj < 2; jj++)
        #pragma unroll
        for (int r = 0; r < 4; r++)
            Xl[(qd * 4 + r) * XS + (w * 2 + jj) * 16 + lr] = f2bs(vals[jj][r]);
    if (t < 8)
        part_out[(size_t)bi * 16 + t] = pw[t >> 1][t & 1];
    else if (t < 16) {
        int g = t - 8;
        part_out[(size_t)bi * 16 + t] = pw[g >> 1][2 + (g & 1)];
    }
    __syncthreads();

    // ---- store h (coalesced) ----
    {
        int flat = t * 8;
        int row = flat >> 7, col = flat & 127;
        *(short8*)(hout + (size_t)bi * (MRPB * CH) + flat) =
            *(const short8*)&Xl[row * XS + col];
    }
}

// ---------------- final GN + LeakyReLU -> f32 out (16-row tiles) ----------------
__global__ __launch_bounds__(256) void k_out(
    const unsigned short* __restrict__ hin, const float* __restrict__ part_in,
    const float* __restrict__ gamma, const float* __restrict__ beta,
    float* __restrict__ out)
{
    const int bi = blockIdx.x;                // 0..2047
    const int t  = threadIdx.x;
    const int b  = bi / MBPB;
    __shared__ float red[16][17];
    __shared__ float2 stats_s[NG];
    constexpr int PPB = 512;                  // partial rows/batch (from mid)
    constexpr int R = PPB / 16;
    {
        int j = t & 15, chunk = t >> 4;
        float acc = 0.f;
        #pragma unroll
        for (int i = 0; i < R; i++)
            acc += part_in[(size_t)(b * PPB + chunk * R + i) * 16 + j];
        red[chunk][j] = acc;
    }
    __syncthreads();
    if (t < NG) {
        float s = 0.f, q = 0.f;
        #pragma unroll
        for (int c = 0; c < 16; c++) { s += red[c][t]; q += red[c][t + 8]; }
        const float cnt = (float)(NPB * CG);
        float mean = s / cnt;
        float var  = q / cnt - mean * mean;
        stats_s[t] = make_float2(mean, rsqrtf(var + 1e-5f));
    }
    __syncthreads();
    {
        int flat = t * 8;
        int col = flat & 127;
        size_t gidx = (size_t)bi * (MRPB * CH) + flat;
        short8 hv = *(const short8*)(hin + gidx);
        float2 st = stats_s[col >> 4];
        float4 g0 = *(const float4*)(gamma + col);
        float4 g1 = *(const float4*)(gamma + col + 4);
        float4 b0 = *(const float4*)(beta + col);
        float4 b1 = *(const float4*)(beta + col + 4);
        float gg[8] = {g0.x, g0.y, g0.z, g0.w, g1.x, g1.y, g1.z, g1.w};
        float bb[8] = {b0.x, b0.y, b0.z, b0.w, b1.x, b1.y, b1.z, b1.w};
        float o[8];
        #pragma unroll
        for (int e = 0; e < 8; e++) {
            float v = bs2f((unsigned short)hv[e]);
            float y = (v - st.x) * st.y * gg[e] + bb[e];
            o[e] = (y >= 0.f) ? y : 0.1f * y;
        }
        float4 o0 = {o[0], o[1], o[2], o[3]};
        float4 o1 = {o[4], o[5], o[6], o[7]};
        *(float4*)(out + gidx)     = o0;
        *(float4*)(out + gidx + 4) = o1;
    }
}

extern "C" void kernel_launch(void* const* d_in, const int* in_sizes, int n_in,
                              void* d_out, int out_size, void* d_ws, size_t ws_size,
                              hipStream_t stream) {
    const float* qf  = (const float*)d_in[0];
    const float* sf  = (const float*)d_in[1];
    const float* qp  = (const float*)d_in[2];
    const float* sp  = (const float*)d_in[3];
    const int*   idx = (const int*)  d_in[4];
    const float* W1  = (const float*)d_in[5];
    const float* b1  = (const float*)d_in[6];
    const float* g1  = (const float*)d_in[7];
    const float* be1 = (const float*)d_in[8];
    const float* W2  = (const float*)d_in[9];
    const float* b2  = (const float*)d_in[10];
    const float* g2  = (const float*)d_in[11];
    const float* be2 = (const float*)d_in[12];
    const float* W3  = (const float*)d_in[13];
    const float* b3  = (const float*)d_in[14];
    const float* g3  = (const float*)d_in[15];
    const float* be3 = (const float*)d_in[16];

    char* ws = (char*)d_ws;
    unsigned short* Wt1 = (unsigned short*)(ws);
    unsigned short* Wf2 = (unsigned short*)(ws + 32768);
    unsigned short* Wf3 = (unsigned short*)(ws + 65536);
    float* p1 = (float*)(ws + 98304);                    // 512*16*4  = 32 KB
    float* p2 = (float*)(ws + 131072);                   // 2048*16*4 = 128 KB
    float* p3 = (float*)(ws + 262144);                   // 2048*16*4 = 128 KB
    unsigned short* h1 = (unsigned short*)(ws + 393216);             // 8 MB
    unsigned short* h2 = (unsigned short*)(ws + 393216 + 8388608);   // 8 MB
    unsigned short* h3 = (unsigned short*)(ws + 393216 + 2 * 8388608);
    float* out = (float*)d_out;

    k_prep<<<192, 256, 0, stream>>>(W1, W2, W3, Wt1, Wf2, Wf3);
    k_head<<<NBLK, 256, 0, stream>>>(sf, qp, sp, idx, Wt1, b1, h1, p1);
    k_mid<0, 128><<<MNBLK, 256, 0, stream>>>(h1, p1, g1, be1, nullptr, Wf2, b2, h2, p2);
    k_mid<1, 512><<<MNBLK, 256, 0, stream>>>(h2, p2, g2, be2, qf, Wf3, b3, h3, p3);
    k_out<<<MNBLK, 256, 0, stream>>>(h3, p3, g3, be3, out);
}

// Round 11
// 192.972 us; speedup vs baseline: 1.9504x; 1.0113x over previous
//
#include <hip/hip_runtime.h>

// Downsampling_77214922047594 — B=4, N=8192, M=32768, K=16, C=128, G=8, f32 I/O
// Round 12: accounting across rounds shows ~111 µs FIXED harness overhead in
// dur_us + ~84 µs of real kernel time (head 48, mids ~11 each). Target k_head:
//  - delete W LDS tile (B-operand from global fragment-major Wf1, proven in
//    round-10 mids) -> LDS 63 KB -> ~24 KB -> 2 -> 6 blocks/CU (3x waves for
//    the latency-bound random gather)
//  - XCD swizzle (2 XCDs/batch): per-XCD gather working set 64 -> 16 MB
//  - gather loop body untouched (round-5 lesson); mids/out = round-10 proven

constexpr int NPB = 8192;            // N per batch
constexpr int BN  = 32768;           // total rows
constexpr int CH  = 128;
constexpr int KNB = 16;              // neighbors
constexpr int MS  = 32768;           // s_feats rows per batch
constexpr int NG  = 8;               // groups
constexpr int CG  = 16;              // channels per group
constexpr int RPB = 64;              // k_head rows per block
constexpr int NBLK = BN / RPB;       // 512 blocks (head)
constexpr int BPB  = NPB / RPB;      // 128 head blocks per batch
constexpr int MRPB = 16;             // mid/out rows per block
constexpr int MNBLK = BN / MRPB;     // 2048 blocks (mid/out)
constexpr int MBPB  = NPB / MRPB;    // 512 mid blocks per batch
constexpr int XS = 152;              // LDS stride (shorts): 304B rows -> 2-way banks

typedef short short8 __attribute__((ext_vector_type(8)));
typedef float floatx4 __attribute__((ext_vector_type(4)));

static __device__ __forceinline__ unsigned short f2bs(float f) {
    unsigned int u = __builtin_bit_cast(unsigned int, f);
    unsigned int r = (u + 0x7fffu + ((u >> 16) & 1u)) >> 16;   // RNE
    return (unsigned short)r;
}
static __device__ __forceinline__ float bs2f(unsigned short s) {
    unsigned int u = ((unsigned int)s) << 16;
    return __builtin_bit_cast(float, u);
}

// ---------------- W prep: ALL layers fragment-major ----------------
// Wf[((j*4+kt)*64+lane)*8+e] = bf16(W[k][n]), n=j*16+lr, k=kt*32+qd*8+e,
// lane=qd*16+lr  => per (j,kt) a wave loads 1 KB contiguous.
__global__ __launch_bounds__(256) void k_prep(
    const float* __restrict__ W1, const float* __restrict__ W2,
    const float* __restrict__ W3,
    unsigned short* __restrict__ Wf1, unsigned short* __restrict__ Wf2,
    unsigned short* __restrict__ Wf3)
{
    const int bi = blockIdx.x;          // 0..191
    const int w  = bi >> 6;
    const int i  = bi & 63;
    const int el = i * 256 + threadIdx.x;
    const int n  = el >> 7, k = el & 127;
    const float* W = (w == 0) ? W1 : (w == 1) ? W2 : W3;
    unsigned short v = f2bs(W[k * 128 + n]);
    unsigned short* Wf = (w == 0) ? Wf1 : (w == 1) ? Wf2 : Wf3;
    int j = n >> 4, lr = n & 15;
    int kt = k >> 5, qd = (k >> 3) & 3, e = k & 7;
    Wf[(((j * 4 + kt) * 64) + (qd * 16 + lr)) * 8 + e] = v;
}

// ---------------- head: IDW gather + GEMM1 -> h1 bf16 + partials ----------------
// Gather loop = proven round-0 body. No W LDS tile; XCD-swizzled block map.
__global__ __launch_bounds__(256) void k_head(
    const float* __restrict__ sf, const float* __restrict__ qp,
    const float* __restrict__ sp, const int* __restrict__ idx,
    const unsigned short* __restrict__ Wf,    // fragment-major bf16 128x128
    const float* __restrict__ bias,           // b1
    unsigned short* __restrict__ hout,        // bf16 (BN,CH) pre-GN
    float* __restrict__ part_out)             // (NBLK,16)
{
    // XCD swizzle: 2 XCDs per batch -> per-XCD gather working set = one batch
    const int rep = blockIdx.x & 7;
    const int q8  = blockIdx.x >> 3;                   // 0..63
    const int bi  = (rep >> 1) * BPB + (rep & 1) * 64 + q8;
    const int b   = rep >> 1;
    const int t   = threadIdx.x;

    __shared__ unsigned short Xl[RPB * XS];   // 19456 B
    __shared__ float wv[RPB * KNB];           // 4096 B
    __shared__ float winv[RPB];
    __shared__ float pw[4][16];

    // ---- IDW weights ----
    #pragma unroll
    for (int i = 0; i < 4; i++) {
        int p = i * 256 + t;                 // (row, k) pair index
        int row = p >> 4, k = p & 15;
        size_t rg = (size_t)bi * RPB + row;
        float qx = qp[rg * 3 + 0], qy = qp[rg * 3 + 1], qz = qp[rg * 3 + 2];
        const float* spp = sp + (rg * KNB + k) * 3;
        float dx = spp[0] - qx, dy = spp[1] - qy, dz = spp[2] - qz;
        wv[p] = 1.0f / (dx * dx + dy * dy + dz * dz + 1e-8f);
    }
    __syncthreads();
    if (t < RPB) {
        float s = 0.f;
        #pragma unroll
        for (int k = 0; k < KNB; k++) s += wv[t * KNB + k];
        winv[t] = 1.0f / s;
    }
    __syncthreads();
    // ---- gather: proven body, untouched ----
    {
        const int grp = t >> 5, c4 = (t & 31) * 4;
        for (int rr = 0; rr < 8; rr++) {
            int row = grp * 8 + rr;
            size_t rg = (size_t)bi * RPB + row;
            const int* ip = idx + rg * KNB;
            float ax = 0.f, ay = 0.f, az = 0.f, aw = 0.f;
            #pragma unroll
            for (int k = 0; k < KNB; k++) {
                int j = ip[k];
                const float4 f = *(const float4*)(sf + ((size_t)b * MS + j) * CH + c4);
                float w = wv[row * KNB + k];
                ax += w * f.x; ay += w * f.y; az += w * f.z; aw += w * f.w;
            }
            float wi = winv[row];
            ushort4 pk;
            pk.x = f2bs(ax * wi); pk.y = f2bs(ay * wi);
            pk.z = f2bs(az * wi); pk.w = f2bs(aw * wi);
            *(ushort4*)&Xl[row * XS + c4] = pk;
        }
    }
    __syncthreads();

    // ---- MFMA: A from Xl, B from global fragment-major Wf (L2-broadcast) ----
    const int w  = t >> 6;
    const int l  = t & 63;
    const int lr = l & 15;
    const int qd = l >> 4;
    floatx4 acc[8] = {};
    #pragma unroll
    for (int kt = 0; kt < 4; kt++) {
        short8 a = *(const short8*)&Xl[(w * 16 + lr) * XS + kt * 32 + qd * 8];
        #pragma unroll
        for (int j = 0; j < 8; j++) {
            short8 bf = *(const short8*)(Wf + (((j * 4 + kt) * 64) + l) * 8);
            acc[j] = __builtin_amdgcn_mfma_f32_16x16x32_bf16(a, bf, acc[j], 0, 0, 0);
        }
    }

    // ---- epilogue: bias, group partials, store h ----
    float vals[8][4];
    #pragma unroll
    for (int j = 0; j < 8; j++) {
        float bj = bias[j * 16 + lr];
        float ss = 0.f, qq = 0.f;
        #pragma unroll
        for (int r = 0; r < 4; r++) {
            float v = acc[j][r] + bj;
            vals[j][r] = v;
            ss += v; qq += v * v;
        }
        #pragma unroll
        for (int off = 32; off; off >>= 1) {
            ss += __shfl_down(ss, off);
            qq += __shfl_down(qq, off);
        }
        if (l == 0) { pw[w][j] = ss; pw[w][8 + j] = qq; }
    }
    // wave w owns rows [w*16, w*16+16) — no race
    #pragma unroll
    for (int j = 0; j < 8; j++)
        #pragma unroll
        for (int r = 0; r < 4; r++)
            Xl[(w * 16 + qd * 4 + r) * XS + j * 16 + lr] = f2bs(vals[j][r]);
    __syncthreads();
    if (t < 16)
        part_out[(size_t)bi * 16 + t] = pw[0][t] + pw[1][t] + pw[2][t] + pw[3][t];
    #pragma unroll
    for (int i = 0; i < 4; i++) {
        int flat = i * 2048 + t * 8;
        int row = flat >> 7, col = flat & 127;
        *(short8*)(hout + (size_t)bi * RPB * CH + flat) =
            *(const short8*)&Xl[row * XS + col];
    }
}

// ---------------- mid: 16-row tile, 2048 blocks (round-10 proven) ----------------
template <int RESID, int PPB>
__global__ __launch_bounds__(256) void k_mid(
    const unsigned short* __restrict__ hin,   // bf16 pre-GN h
    const float* __restrict__ part_in,
    const float* __restrict__ gamma,          // prev layer GN
    const float* __restrict__ beta,
    const float* __restrict__ qf,             // residual f32 (RESID)
    const unsigned short* __restrict__ Wf,    // fragment-major bf16 128x128
    const float* __restrict__ bias,           // this layer's bias
    unsigned short* __restrict__ hout,        // bf16 (BN,CH) pre-GN
    float* __restrict__ part_out)             // (MNBLK,16)
{
    const int bi = blockIdx.x;                // 0..2047
    const int t  = threadIdx.x;
    const int b  = bi / MBPB;

    __shared__ unsigned short Xl[MRPB * XS];  // 4864 B
    __shared__ float red[16][17];
    __shared__ float2 stats_s[NG];
    __shared__ float pw[4][4];

    // ---- stats re-reduce ----
    constexpr int R = PPB / 16;
    {
        int j = t & 15, chunk = t >> 4;
        float acc = 0.f;
        #pragma unroll
        for (int i = 0; i < R; i++)
            acc += part_in[(size_t)(b * PPB + chunk * R + i) * 16 + j];
        red[chunk][j] = acc;
    }
    __syncthreads();
    if (t < NG) {
        float s = 0.f, q = 0.f;
        #pragma unroll
        for (int c = 0; c < 16; c++) { s += red[c][t]; q += red[c][t + 8]; }
        const float cnt = (float)(NPB * CG);
        float mean = s / cnt;
        float var  = q / cnt - mean * mean;
        stats_s[t] = make_float2(mean, rsqrtf(var + 1e-5f));
    }
    __syncthreads();

    // ---- GN + LeakyReLU (+resid) -> bf16 X tile ----
    {
        int flat = t * 8;
        int row = flat >> 7, col = flat & 127;
        size_t gidx = (size_t)bi * (MRPB * CH) + flat;
        short8 hv = *(const short8*)(hin + gidx);
        float2 st = stats_s[col >> 4];
        float4 g0 = *(const float4*)(gamma + col);
        float4 g1 = *(const float4*)(gamma + col + 4);
        float4 b0 = *(const float4*)(beta + col);
        float4 b1 = *(const float4*)(beta + col + 4);
        float gg[8] = {g0.x, g0.y, g0.z, g0.w, g1.x, g1.y, g1.z, g1.w};
        float bb[8] = {b0.x, b0.y, b0.z, b0.w, b1.x, b1.y, b1.z, b1.w};
        float re[8];
        if (RESID) {
            float4 r0 = *(const float4*)(qf + gidx);
            float4 r1 = *(const float4*)(qf + gidx + 4);
            re[0]=r0.x; re[1]=r0.y; re[2]=r0.z; re[3]=r0.w;
            re[4]=r1.x; re[5]=r1.y; re[6]=r1.z; re[7]=r1.w;
        }
        unsigned short ov[8];
        #pragma unroll
        for (int e = 0; e < 8; e++) {
            float v = bs2f((unsigned short)hv[e]);
            float y = (v - st.x) * st.y * gg[e] + bb[e];
            y = (y >= 0.f) ? y : 0.1f * y;
            if (RESID) y += re[e];
            ov[e] = f2bs(y);
        }
        *(short8*)&Xl[row * XS + col] = *(short8*)ov;
    }
    __syncthreads();

    // ---- MFMA: wave w -> n-tiles {2w, 2w+1}, rows 0..15 ----
    const int w  = t >> 6;
    const int l  = t & 63;
    const int lr = l & 15;
    const int qd = l >> 4;
    floatx4 acc2[2] = {};
    #pragma unroll
    for (int kt = 0; kt < 4; kt++) {
        short8 a = *(const short8*)&Xl[lr * XS + kt * 32 + qd * 8];
        #pragma unroll
        for (int jj = 0; jj < 2; jj++) {
            int j = w * 2 + jj;
            short8 bf = *(const short8*)(Wf + (((j * 4 + kt) * 64) + l) * 8);
            acc2[jj] = __builtin_amdgcn_mfma_f32_16x16x32_bf16(a, bf, acc2[jj], 0, 0, 0);
        }
    }

    // ---- epilogue: bias, group partials ----
    float vals[2][4];
    #pragma unroll
    for (int jj = 0; jj < 2; jj++) {
        int j = w * 2 + jj;
        float bj = bias[j * 16 + lr];
        float ss = 0.f, qq = 0.f;
        #pragma unroll
        for (int r = 0; r < 4; r++) {
            float v = acc2[jj][r] + bj;
            vals[jj][r] = v;
            ss += v; qq += v * v;
        }
        #pragma unroll
        for (int off = 32; off; off >>= 1) {
            ss += __shfl_down(ss, off);
            qq += __shfl_down(qq, off);
        }
        if (l == 0) { pw[w][jj] = ss; pw[w][2 + jj] = qq; }
    }
    __syncthreads();   // all waves done READING Xl (A frags shared) + pw ready

    // ---- scatter C into Xl (disjoint col ranges) + partials out ----
    #pragma unroll
    for (int jj = 0; jj < 2; jj++)
        #pragma unroll
        for (int r = 0; r < 4; r++)
            Xl[(qd * 4 + r) * XS + (w * 2 + jj) * 16 + lr] = f2bs(vals[jj][r]);
    if (t < 8)
        part_out[(size_t)bi * 16 + t] = pw[t >> 1][t & 1];
    else if (t < 16) {
        int g = t - 8;
        part_out[(size_t)bi * 16 + t] = pw[g >> 1][2 + (g & 1)];
    }
    __syncthreads();

    // ---- store h (coalesced) ----
    {
        int flat = t * 8;
        int row = flat >> 7, col = flat & 127;
        *(short8*)(hout + (size_t)bi * (MRPB * CH) + flat) =
            *(const short8*)&Xl[row * XS + col];
    }
}

// ---------------- final GN + LeakyReLU -> f32 out (16-row tiles) ----------------
__global__ __launch_bounds__(256) void k_out(
    const unsigned short* __restrict__ hin, const float* __restrict__ part_in,
    const float* __restrict__ gamma, const float* __restrict__ beta,
    float* __restrict__ out)
{
    const int bi = blockIdx.x;                // 0..2047
    const int t  = threadIdx.x;
    const int b  = bi / MBPB;
    __shared__ float red[16][17];
    __shared__ float2 stats_s[NG];
    constexpr int PPB = 512;                  // partial rows/batch (from mid)
    constexpr int R = PPB / 16;
    {
        int j = t & 15, chunk = t >> 4;
        float acc = 0.f;
        #pragma unroll
        for (int i = 0; i < R; i++)
            acc += part_in[(size_t)(b * PPB + chunk * R + i) * 16 + j];
        red[chunk][j] = acc;
    }
    __syncthreads();
    if (t < NG) {
        float s = 0.f, q = 0.f;
        #pragma unroll
        for (int c = 0; c < 16; c++) { s += red[c][t]; q += red[c][t + 8]; }
        const float cnt = (float)(NPB * CG);
        float mean = s / cnt;
        float var  = q / cnt - mean * mean;
        stats_s[t] = make_float2(mean, rsqrtf(var + 1e-5f));
    }
    __syncthreads();
    {
        int flat = t * 8;
        int col = flat & 127;
        size_t gidx = (size_t)bi * (MRPB * CH) + flat;
        short8 hv = *(const short8*)(hin + gidx);
        float2 st = stats_s[col >> 4];
        float4 g0 = *(const float4*)(gamma + col);
        float4 g1 = *(const float4*)(gamma + col + 4);
        float4 b0 = *(const float4*)(beta + col);
        float4 b1 = *(const float4*)(beta + col + 4);
        float gg[8] = {g0.x, g0.y, g0.z, g0.w, g1.x, g1.y, g1.z, g1.w};
        float bb[8] = {b0.x, b0.y, b0.z, b0.w, b1.x, b1.y, b1.z, b1.w};
        float o[8];
        #pragma unroll
        for (int e = 0; e < 8; e++) {
            float v = bs2f((unsigned short)hv[e]);
            float y = (v - st.x) * st.y * gg[e] + bb[e];
            o[e] = (y >= 0.f) ? y : 0.1f * y;
        }
        float4 o0 = {o[0], o[1], o[2], o[3]};
        float4 o1 = {o[4], o[5], o[6], o[7]};
        *(float4*)(out + gidx)     = o0;
        *(float4*)(out + gidx + 4) = o1;
    }
}

extern "C" void kernel_launch(void* const* d_in, const int* in_sizes, int n_in,
                              void* d_out, int out_size, void* d_ws, size_t ws_size,
                              hipStream_t stream) {
    const float* qf  = (const float*)d_in[0];
    const float* sf  = (const float*)d_in[1];
    const float* qp  = (const float*)d_in[2];
    const float* sp  = (const float*)d_in[3];
    const int*   idx = (const int*)  d_in[4];
    const float* W1  = (const float*)d_in[5];
    const float* b1  = (const float*)d_in[6];
    const float* g1  = (const float*)d_in[7];
    const float* be1 = (const float*)d_in[8];
    const float* W2  = (const float*)d_in[9];
    const float* b2  = (const float*)d_in[10];
    const float* g2  = (const float*)d_in[11];
    const float* be2 = (const float*)d_in[12];
    const float* W3  = (const float*)d_in[13];
    const float* b3  = (const float*)d_in[14];
    const float* g3  = (const float*)d_in[15];
    const float* be3 = (const float*)d_in[16];

    char* ws = (char*)d_ws;
    unsigned short* Wf1 = (unsigned short*)(ws);
    unsigned short* Wf2 = (unsigned short*)(ws + 32768);
    unsigned short* Wf3 = (unsigned short*)(ws + 65536);
    float* p1 = (float*)(ws + 98304);                    // 512*16*4  = 32 KB
    float* p2 = (float*)(ws + 131072);                   // 2048*16*4 = 128 KB
    float* p3 = (float*)(ws + 262144);                   // 2048*16*4 = 128 KB
    unsigned short* h1 = (unsigned short*)(ws + 393216);             // 8 MB
    unsigned short* h2 = (unsigned short*)(ws + 393216 + 8388608);   // 8 MB
    unsigned short* h3 = (unsigned short*)(ws + 393216 + 2 * 8388608);
    float* out = (float*)d_out;

    k_prep<<<192, 256, 0, stream>>>(W1, W2, W3, Wf1, Wf2, Wf3);
    k_head<<<NBLK, 256, 0, stream>>>(sf, qp, sp, idx, Wf1, b1, h1, p1);
    k_mid<0, 128><<<MNBLK, 256, 0, stream>>>(h1, p1, g1, be1, nullptr, Wf2, b2, h2, p2);
    k_mid<1, 512><<<MNBLK, 256, 0, stream>>>(h2, p2, g2, be2, qf, Wf3, b3, h3, p3);
    k_out<<<MNBLK, 256, 0, stream>>>(h3, p3, g3, be3, out);
}

// Round 12
// 190.925 us; speedup vs baseline: 1.9713x; 1.0107x over previous
//
#include <hip/hip_runtime.h>

// Downsampling_77214922047594 — B=4, N=8192, M=32768, K=16, C=128, G=8, f32 I/O
// Round 13: k_head gets real occupancy. Round 11 raised LDS capacity (24 KB)
// but grid stayed 512 = 2 blocks/CU — occupancy = min(capacity, grid/CU).
// Now k_head uses 16-row tiles -> 2048 blocks = 8/CU = 32 waves/CU (4x) for
// the latency-bound random gather. Gather inner body byte-identical; MFMA =
// mid-proven column-split. Mids/out = round-10/11 proven (layer-2 PPB=512).

constexpr int NPB = 8192;            // N per batch
constexpr int BN  = 32768;           // total rows
constexpr int CH  = 128;
constexpr int KNB = 16;              // neighbors
constexpr int MS  = 32768;           // s_feats rows per batch
constexpr int NG  = 8;               // groups
constexpr int CG  = 16;              // channels per group
constexpr int MRPB = 16;             // rows per block (all passes now)
constexpr int MNBLK = BN / MRPB;     // 2048 blocks
constexpr int MBPB  = NPB / MRPB;    // 512 blocks per batch
constexpr int XS = 152;              // LDS stride (shorts): 304B rows -> 2-way banks

typedef short short8 __attribute__((ext_vector_type(8)));
typedef float floatx4 __attribute__((ext_vector_type(4)));

static __device__ __forceinline__ unsigned short f2bs(float f) {
    unsigned int u = __builtin_bit_cast(unsigned int, f);
    unsigned int r = (u + 0x7fffu + ((u >> 16) & 1u)) >> 16;   // RNE
    return (unsigned short)r;
}
static __device__ __forceinline__ float bs2f(unsigned short s) {
    unsigned int u = ((unsigned int)s) << 16;
    return __builtin_bit_cast(float, u);
}

// ---------------- W prep: ALL layers fragment-major ----------------
// Wf[((j*4+kt)*64+lane)*8+e] = bf16(W[k][n]), n=j*16+lr, k=kt*32+qd*8+e,
// lane=qd*16+lr  => per (j,kt) a wave loads 1 KB contiguous.
__global__ __launch_bounds__(256) void k_prep(
    const float* __restrict__ W1, const float* __restrict__ W2,
    const float* __restrict__ W3,
    unsigned short* __restrict__ Wf1, unsigned short* __restrict__ Wf2,
    unsigned short* __restrict__ Wf3)
{
    const int bi = blockIdx.x;          // 0..191
    const int w  = bi >> 6;
    const int i  = bi & 63;
    const int el = i * 256 + threadIdx.x;
    const int n  = el >> 7, k = el & 127;
    const float* W = (w == 0) ? W1 : (w == 1) ? W2 : W3;
    unsigned short v = f2bs(W[k * 128 + n]);
    unsigned short* Wf = (w == 0) ? Wf1 : (w == 1) ? Wf2 : Wf3;
    int j = n >> 4, lr = n & 15;
    int kt = k >> 5, qd = (k >> 3) & 3, e = k & 7;
    Wf[(((j * 4 + kt) * 64) + (qd * 16 + lr)) * 8 + e] = v;
}

// ---------------- head: IDW gather + GEMM1, 16-row tiles, 2048 blocks --------
__global__ __launch_bounds__(256) void k_head(
    const float* __restrict__ sf, const float* __restrict__ qp,
    const float* __restrict__ sp, const int* __restrict__ idx,
    const unsigned short* __restrict__ Wf,    // fragment-major bf16 128x128
    const float* __restrict__ bias,           // b1
    unsigned short* __restrict__ hout,        // bf16 (BN,CH) pre-GN
    float* __restrict__ part_out)             // (MNBLK,16)
{
    // XCD swizzle: 2 XCDs per batch -> per-XCD gather working set = one batch
    const int rep = blockIdx.x & 7;
    const int q8  = blockIdx.x >> 3;                   // 0..255
    const int bi  = (rep >> 1) * MBPB + (rep & 1) * 256 + q8;
    const int b   = rep >> 1;
    const int t   = threadIdx.x;

    __shared__ unsigned short Xl[MRPB * XS];  // 4864 B
    __shared__ float wv[MRPB * KNB];          // 1024 B
    __shared__ float winv[MRPB];
    __shared__ float pw[4][4];

    // ---- IDW weights: one (row,k) pair per thread ----
    {
        int row = t >> 4, k = t & 15;
        size_t rg = (size_t)bi * MRPB + row;
        float qx = qp[rg * 3 + 0], qy = qp[rg * 3 + 1], qz = qp[rg * 3 + 2];
        const float* spp = sp + (rg * KNB + k) * 3;
        float dx = spp[0] - qx, dy = spp[1] - qy, dz = spp[2] - qz;
        wv[t] = 1.0f / (dx * dx + dy * dy + dz * dz + 1e-8f);
    }
    __syncthreads();
    if (t < MRPB) {
        float s = 0.f;
        #pragma unroll
        for (int k = 0; k < KNB; k++) s += wv[t * KNB + k];
        winv[t] = 1.0f / s;
    }
    __syncthreads();
    // ---- gather: proven inner body; 8 groups x 32 lanes, 2 rows each ----
    {
        const int grp = t >> 5, c4 = (t & 31) * 4;
        for (int rr = 0; rr < 2; rr++) {
            int row = grp * 2 + rr;
            size_t rg = (size_t)bi * MRPB + row;
            const int* ip = idx + rg * KNB;
            float ax = 0.f, ay = 0.f, az = 0.f, aw = 0.f;
            #pragma unroll
            for (int k = 0; k < KNB; k++) {
                int j = ip[k];
                const float4 f = *(const float4*)(sf + ((size_t)b * MS + j) * CH + c4);
                float w = wv[row * KNB + k];
                ax += w * f.x; ay += w * f.y; az += w * f.z; aw += w * f.w;
            }
            float wi = winv[row];
            ushort4 pk;
            pk.x = f2bs(ax * wi); pk.y = f2bs(ay * wi);
            pk.z = f2bs(az * wi); pk.w = f2bs(aw * wi);
            *(ushort4*)&Xl[row * XS + c4] = pk;
        }
    }
    __syncthreads();

    // ---- MFMA: wave w -> n-tiles {2w, 2w+1}, rows 0..15 (column-split) ----
    const int w  = t >> 6;
    const int l  = t & 63;
    const int lr = l & 15;
    const int qd = l >> 4;
    floatx4 acc2[2] = {};
    #pragma unroll
    for (int kt = 0; kt < 4; kt++) {
        short8 a = *(const short8*)&Xl[lr * XS + kt * 32 + qd * 8];
        #pragma unroll
        for (int jj = 0; jj < 2; jj++) {
            int j = w * 2 + jj;
            short8 bf = *(const short8*)(Wf + (((j * 4 + kt) * 64) + l) * 8);
            acc2[jj] = __builtin_amdgcn_mfma_f32_16x16x32_bf16(a, bf, acc2[jj], 0, 0, 0);
        }
    }

    // ---- epilogue: bias, group partials ----
    float vals[2][4];
    #pragma unroll
    for (int jj = 0; jj < 2; jj++) {
        int j = w * 2 + jj;
        float bj = bias[j * 16 + lr];
        float ss = 0.f, qq = 0.f;
        #pragma unroll
        for (int r = 0; r < 4; r++) {
            float v = acc2[jj][r] + bj;
            vals[jj][r] = v;
            ss += v; qq += v * v;
        }
        #pragma unroll
        for (int off = 32; off; off >>= 1) {
            ss += __shfl_down(ss, off);
            qq += __shfl_down(qq, off);
        }
        if (l == 0) { pw[w][jj] = ss; pw[w][2 + jj] = qq; }
    }
    __syncthreads();   // all waves done READING Xl (A frags shared) + pw ready

    // ---- scatter C into Xl (disjoint col ranges) + partials out ----
    #pragma unroll
    for (int jj = 0; jj < 2; jj++)
        #pragma unroll
        for (int r = 0; r < 4; r++)
            Xl[(qd * 4 + r) * XS + (w * 2 + jj) * 16 + lr] = f2bs(vals[jj][r]);
    if (t < 8)
        part_out[(size_t)bi * 16 + t] = pw[t >> 1][t & 1];
    else if (t < 16) {
        int g = t - 8;
        part_out[(size_t)bi * 16 + t] = pw[g >> 1][2 + (g & 1)];
    }
    __syncthreads();

    // ---- store h (coalesced) ----
    {
        int flat = t * 8;
        int row = flat >> 7, col = flat & 127;
        *(short8*)(hout + (size_t)bi * (MRPB * CH) + flat) =
            *(const short8*)&Xl[row * XS + col];
    }
}

// ---------------- mid: 16-row tile, 2048 blocks (round-10 proven) ----------------
template <int RESID>
__global__ __launch_bounds__(256) void k_mid(
    const unsigned short* __restrict__ hin,   // bf16 pre-GN h
    const float* __restrict__ part_in,        // (MNBLK,16), 512 rows/batch
    const float* __restrict__ gamma,          // prev layer GN
    const float* __restrict__ beta,
    const float* __restrict__ qf,             // residual f32 (RESID)
    const unsigned short* __restrict__ Wf,    // fragment-major bf16 128x128
    const float* __restrict__ bias,           // this layer's bias
    unsigned short* __restrict__ hout,        // bf16 (BN,CH) pre-GN
    float* __restrict__ part_out)             // (MNBLK,16)
{
    const int bi = blockIdx.x;                // 0..2047
    const int t  = threadIdx.x;
    const int b  = bi / MBPB;

    __shared__ unsigned short Xl[MRPB * XS];  // 4864 B
    __shared__ float red[16][17];
    __shared__ float2 stats_s[NG];
    __shared__ float pw[4][4];

    // ---- stats re-reduce (512 partial rows/batch) ----
    constexpr int R = 32;                     // 512 / 16
    {
        int j = t & 15, chunk = t >> 4;
        float acc = 0.f;
        #pragma unroll
        for (int i = 0; i < R; i++)
            acc += part_in[(size_t)(b * 512 + chunk * R + i) * 16 + j];
        red[chunk][j] = acc;
    }
    __syncthreads();
    if (t < NG) {
        float s = 0.f, q = 0.f;
        #pragma unroll
        for (int c = 0; c < 16; c++) { s += red[c][t]; q += red[c][t + 8]; }
        const float cnt = (float)(NPB * CG);
        float mean = s / cnt;
        float var  = q / cnt - mean * mean;
        stats_s[t] = make_float2(mean, rsqrtf(var + 1e-5f));
    }
    __syncthreads();

    // ---- GN + LeakyReLU (+resid) -> bf16 X tile ----
    {
        int flat = t * 8;
        int row = flat >> 7, col = flat & 127;
        size_t gidx = (size_t)bi * (MRPB * CH) + flat;
        short8 hv = *(const short8*)(hin + gidx);
        float2 st = stats_s[col >> 4];
        float4 g0 = *(const float4*)(gamma + col);
        float4 g1 = *(const float4*)(gamma + col + 4);
        float4 b0 = *(const float4*)(beta + col);
        float4 b1 = *(const float4*)(beta + col + 4);
        float gg[8] = {g0.x, g0.y, g0.z, g0.w, g1.x, g1.y, g1.z, g1.w};
        float bb[8] = {b0.x, b0.y, b0.z, b0.w, b1.x, b1.y, b1.z, b1.w};
        float re[8];
        if (RESID) {
            float4 r0 = *(const float4*)(qf + gidx);
            float4 r1 = *(const float4*)(qf + gidx + 4);
            re[0]=r0.x; re[1]=r0.y; re[2]=r0.z; re[3]=r0.w;
            re[4]=r1.x; re[5]=r1.y; re[6]=r1.z; re[7]=r1.w;
        }
        unsigned short ov[8];
        #pragma unroll
        for (int e = 0; e < 8; e++) {
            float v = bs2f((unsigned short)hv[e]);
            float y = (v - st.x) * st.y * gg[e] + bb[e];
            y = (y >= 0.f) ? y : 0.1f * y;
            if (RESID) y += re[e];
            ov[e] = f2bs(y);
        }
        *(short8*)&Xl[row * XS + col] = *(short8*)ov;
    }
    __syncthreads();

    // ---- MFMA: wave w -> n-tiles {2w, 2w+1}, rows 0..15 ----
    const int w  = t >> 6;
    const int l  = t & 63;
    const int lr = l & 15;
    const int qd = l >> 4;
    floatx4 acc2[2] = {};
    #pragma unroll
    for (int kt = 0; kt < 4; kt++) {
        short8 a = *(const short8*)&Xl[lr * XS + kt * 32 + qd * 8];
        #pragma unroll
        for (int jj = 0; jj < 2; jj++) {
            int j = w * 2 + jj;
            short8 bf = *(const short8*)(Wf + (((j * 4 + kt) * 64) + l) * 8);
            acc2[jj] = __builtin_amdgcn_mfma_f32_16x16x32_bf16(a, bf, acc2[jj], 0, 0, 0);
        }
    }

    // ---- epilogue: bias, group partials ----
    float vals[2][4];
    #pragma unroll
    for (int jj = 0; jj < 2; jj++) {
        int j = w * 2 + jj;
        float bj = bias[j * 16 + lr];
        float ss = 0.f, qq = 0.f;
        #pragma unroll
        for (int r = 0; r < 4; r++) {
            float v = acc2[jj][r] + bj;
            vals[jj][r] = v;
            ss += v; qq += v * v;
        }
        #pragma unroll
        for (int off = 32; off; off >>= 1) {
            ss += __shfl_down(ss, off);
            qq += __shfl_down(qq, off);
        }
        if (l == 0) { pw[w][jj] = ss; pw[w][2 + jj] = qq; }
    }
    __syncthreads();   // all waves done READING Xl (A frags shared) + pw ready

    // ---- scatter C into Xl (disjoint col ranges) + partials out ----
    #pragma unroll
    for (int jj = 0; jj < 2; jj++)
        #pragma unroll
        for (int r = 0; r < 4; r++)
            Xl[(qd * 4 + r) * XS + (w * 2 + jj) * 16 + lr] = f2bs(vals[jj][r]);
    if (t < 8)
        part_out[(size_t)bi * 16 + t] = pw[t >> 1][t & 1];
    else if (t < 16) {
        int g = t - 8;
        part_out[(size_t)bi * 16 + t] = pw[g >> 1][2 + (g & 1)];
    }
    __syncthreads();

    // ---- store h (coalesced) ----
    {
        int flat = t * 8;
        int row = flat >> 7, col = flat & 127;
        *(short8*)(hout + (size_t)bi * (MRPB * CH) + flat) =
            *(const short8*)&Xl[row * XS + col];
    }
}

// ---------------- final GN + LeakyReLU -> f32 out (16-row tiles) ----------------
__global__ __launch_bounds__(256) void k_out(
    const unsigned short* __restrict__ hin, const float* __restrict__ part_in,
    const float* __restrict__ gamma, const float* __restrict__ beta,
    float* __restrict__ out)
{
    const int bi = blockIdx.x;                // 0..2047
    const int t  = threadIdx.x;
    const int b  = bi / MBPB;
    __shared__ float red[16][17];
    __shared__ float2 stats_s[NG];
    constexpr int R = 32;                     // 512 partial rows/batch
    {
        int j = t & 15, chunk = t >> 4;
        float acc = 0.f;
        #pragma unroll
        for (int i = 0; i < R; i++)
            acc += part_in[(size_t)(b * 512 + chunk * R + i) * 16 + j];
        red[chunk][j] = acc;
    }
    __syncthreads();
    if (t < NG) {
        float s = 0.f, q = 0.f;
        #pragma unroll
        for (int c = 0; c < 16; c++) { s += red[c][t]; q += red[c][t + 8]; }
        const float cnt = (float)(NPB * CG);
        float mean = s / cnt;
        float var  = q / cnt - mean * mean;
        stats_s[t] = make_float2(mean, rsqrtf(var + 1e-5f));
    }
    __syncthreads();
    {
        int flat = t * 8;
        int col = flat & 127;
        size_t gidx = (size_t)bi * (MRPB * CH) + flat;
        short8 hv = *(const short8*)(hin + gidx);
        float2 st = stats_s[col >> 4];
        float4 g0 = *(const float4*)(gamma + col);
        float4 g1 = *(const float4*)(gamma + col + 4);
        float4 b0 = *(const float4*)(beta + col);
        float4 b1 = *(const float4*)(beta + col + 4);
        float gg[8] = {g0.x, g0.y, g0.z, g0.w, g1.x, g1.y, g1.z, g1.w};
        float bb[8] = {b0.x, b0.y, b0.z, b0.w, b1.x, b1.y, b1.z, b1.w};
        float o[8];
        #pragma unroll
        for (int e = 0; e < 8; e++) {
            float v = bs2f((unsigned short)hv[e]);
            float y = (v - st.x) * st.y * gg[e] + bb[e];
            o[e] = (y >= 0.f) ? y : 0.1f * y;
        }
        float4 o0 = {o[0], o[1], o[2], o[3]};
        float4 o1 = {o[4], o[5], o[6], o[7]};
        *(float4*)(out + gidx)     = o0;
        *(float4*)(out + gidx + 4) = o1;
    }
}

extern "C" void kernel_launch(void* const* d_in, const int* in_sizes, int n_in,
                              void* d_out, int out_size, void* d_ws, size_t ws_size,
                              hipStream_t stream) {
    const float* qf  = (const float*)d_in[0];
    const float* sf  = (const float*)d_in[1];
    const float* qp  = (const float*)d_in[2];
    const float* sp  = (const float*)d_in[3];
    const int*   idx = (const int*)  d_in[4];
    const float* W1  = (const float*)d_in[5];
    const float* b1  = (const float*)d_in[6];
    const float* g1  = (const float*)d_in[7];
    const float* be1 = (const float*)d_in[8];
    const float* W2  = (const float*)d_in[9];
    const float* b2  = (const float*)d_in[10];
    const float* g2  = (const float*)d_in[11];
    const float* be2 = (const float*)d_in[12];
    const float* W3  = (const float*)d_in[13];
    const float* b3  = (const float*)d_in[14];
    const float* g3  = (const float*)d_in[15];
    const float* be3 = (const float*)d_in[16];

    char* ws = (char*)d_ws;
    unsigned short* Wf1 = (unsigned short*)(ws);
    unsigned short* Wf2 = (unsigned short*)(ws + 32768);
    unsigned short* Wf3 = (unsigned short*)(ws + 65536);
    float* p1 = (float*)(ws + 98304);                    // 2048*16*4 = 128 KB
    float* p2 = (float*)(ws + 229376);                   // 128 KB
    float* p3 = (float*)(ws + 360448);                   // 128 KB
    unsigned short* h1 = (unsigned short*)(ws + 524288);             // 8 MB
    unsigned short* h2 = (unsigned short*)(ws + 524288 + 8388608);   // 8 MB
    unsigned short* h3 = (unsigned short*)(ws + 524288 + 2 * 8388608);
    float* out = (float*)d_out;

    k_prep<<<192, 256, 0, stream>>>(W1, W2, W3, Wf1, Wf2, Wf3);
    k_head<<<MNBLK, 256, 0, stream>>>(sf, qp, sp, idx, Wf1, b1, h1, p1);
    k_mid<0><<<MNBLK, 256, 0, stream>>>(h1, p1, g1, be1, nullptr, Wf2, b2, h2, p2);
    k_mid<1><<<MNBLK, 256, 0, stream>>>(h2, p2, g2, be2, qf, Wf3, b3, h3, p3);
    k_out<<<MNBLK, 256, 0, stream>>>(h3, p3, g3, be3, out);
}